// Round 1
// baseline (5907.493 us; speedup 1.0000x reference)
//
#include <hip/hip_runtime.h>
#include <hip/hip_bf16.h>
#include <stdint.h>

#define HID 128
#define LAYERS 5

typedef __attribute__((ext_vector_type(8))) short short8;
typedef __attribute__((ext_vector_type(4))) float f32x4;

__device__ __forceinline__ float bf2f(unsigned int u16) {
  union { unsigned int i; float f; } c; c.i = u16 << 16; return c.f;
}
__device__ __forceinline__ unsigned short f2bf(float f) {
  union { float f; unsigned int i; } c; c.f = f;
  unsigned int r = c.i + 0x7fffu + ((c.i >> 16) & 1u);
  return (unsigned short)(r >> 16);
}
__device__ __forceinline__ float siluf(float v) { return v / (1.f + expf(-v)); }

__device__ __forceinline__ float dot8bf(const unsigned short* p, const float* w) {
  uint4 v = *(const uint4*)p;
  float s;
  s  = bf2f(v.x & 0xffffu) * w[0] + bf2f(v.x >> 16) * w[1];
  s += bf2f(v.y & 0xffffu) * w[2] + bf2f(v.y >> 16) * w[3];
  s += bf2f(v.z & 0xffffu) * w[4] + bf2f(v.z >> 16) * w[5];
  s += bf2f(v.w & 0xffffu) * w[6] + bf2f(v.w >> 16) * w[7];
  return s;
}

// ---------------- generic f32 GEMM: out[M,128] = A[M,K] @ W[K,128] + bias ----------------
__global__ void gemm_f32_kernel(const float* __restrict__ A, const float* __restrict__ W,
                                const float* __restrict__ bias, float* __restrict__ out,
                                int M, int K) {
  __shared__ float As[64][33];
  __shared__ float Bs[32][132];
  int tx = threadIdx.x & 15;   // col group: cols tx*8..+7
  int ty = threadIdx.x >> 4;   // row group: rows ty*4..+3
  int row0 = blockIdx.x * 64;
  float acc[4][8] = {};
  for (int k0 = 0; k0 < K; k0 += 32) {
    for (int i = threadIdx.x; i < 64*32; i += 256) {
      int r = i >> 5, c = i & 31;
      int gr = row0 + r, gc = k0 + c;
      As[r][c] = (gr < M && gc < K) ? A[(size_t)gr*K + gc] : 0.f;
    }
    for (int i = threadIdx.x; i < 32*128; i += 256) {
      int r = i >> 7, c = i & 127;
      int gk = k0 + r;
      Bs[r][c] = (gk < K) ? W[(size_t)gk*128 + c] : 0.f;
    }
    __syncthreads();
    #pragma unroll 8
    for (int k = 0; k < 32; ++k) {
      float a[4], b[8];
      #pragma unroll
      for (int i = 0; i < 4; ++i) a[i] = As[ty*4+i][k];
      #pragma unroll
      for (int j = 0; j < 8; ++j) b[j] = Bs[k][tx*8+j];
      #pragma unroll
      for (int i = 0; i < 4; ++i)
        #pragma unroll
        for (int j = 0; j < 8; ++j) acc[i][j] += a[i]*b[j];
    }
    __syncthreads();
  }
  #pragma unroll
  for (int i = 0; i < 4; ++i) {
    int gr = row0 + ty*4 + i;
    if (gr < M) {
      #pragma unroll
      for (int j = 0; j < 8; ++j)
        out[(size_t)gr*128 + tx*8 + j] = acc[i][j] + bias[tx*8 + j];
    }
  }
}

// ---------------- per-feature sum/sumsq over rows: stats[0:128]=sum, [128:256]=sumsq ----
__global__ void colstats_kernel(const float* __restrict__ in, int M, float* __restrict__ stats) {
  int f = threadIdx.x & 127;
  int rl = threadIdx.x >> 7;
  float s = 0, s2 = 0;
  for (int r = blockIdx.x*2 + rl; r < M; r += gridDim.x*2) {
    float v = in[(size_t)r*128 + f];
    s += v; s2 += v*v;
  }
  __shared__ float l1[256], l2[256];
  l1[threadIdx.x] = s; l2[threadIdx.x] = s2;
  __syncthreads();
  if (rl == 0) {
    atomicAdd(&stats[f],       s  + l1[128+f]);
    atomicAdd(&stats[128+f],   s2 + l2[128+f]);
  }
}

// ---------------- BN (+silu / +residual), writes f32 x and bf16 xb -----------------------
template<bool SILU, bool RES>
__global__ void bn_act_kernel(const float* __restrict__ in, const float* __restrict__ stats,
                              const float* __restrict__ g, const float* __restrict__ be,
                              const float* __restrict__ resid, float invM,
                              float* __restrict__ xout, unsigned short* __restrict__ xbout,
                              size_t total) {
  int f = threadIdx.x & 127;
  float mean = stats[f] * invM;
  float var  = stats[128+f] * invM - mean*mean;
  float sc = g[f] * rsqrtf(var + 1e-5f);
  float sh = be[f] - mean * sc;
  for (size_t i = (size_t)blockIdx.x*blockDim.x + threadIdx.x; i < total;
       i += (size_t)gridDim.x*blockDim.x) {
    float v = in[i]*sc + sh;
    if (SILU) v = siluf(v);
    if (RES)  v += resid[i];
    xout[i] = v;
    xbout[i] = f2bf(v);
  }
}

// ---------------- build transposed bf16 Wg for this layer: Wgt[f=h*32+d][k] --------------
__global__ void wgt_prep_kernel(const float* __restrict__ WgL, unsigned short* __restrict__ Wgt) {
  int i = blockIdx.x*256 + threadIdx.x;
  if (i >= 128*256) return;
  int k = i & 255;
  int f = i >> 8;
  int hh = f >> 5, d = f & 31;
  Wgt[i] = f2bf(WgL[((size_t)hh*256 + k)*32 + d]);
}

// ---------------- edge gate: t_e = [x_src,x_dst] . Wf + bf ; + global sum/sumsq ----------
__global__ void gate1_kernel(const unsigned short* __restrict__ xb, const int* __restrict__ src,
                             const int* __restrict__ dst, const float* __restrict__ WfL,
                             const float* __restrict__ bfL, float* __restrict__ t,
                             float* __restrict__ gstats, int E) {
  __shared__ float wf[256];
  wf[threadIdx.x] = WfL[threadIdx.x];
  __syncthreads();
  float bf0 = bfL[0];
  float s = 0, s2 = 0;
  for (int e = blockIdx.x*blockDim.x + threadIdx.x; e < E; e += gridDim.x*blockDim.x) {
    const unsigned short* ps = xb + ((size_t)src[e] << 7);
    const unsigned short* pd = xb + ((size_t)dst[e] << 7);
    float acc = bf0;
    #pragma unroll
    for (int k = 0; k < 128; k += 8) acc += dot8bf(ps + k, wf + k);
    #pragma unroll
    for (int k = 0; k < 128; k += 8) acc += dot8bf(pd + k, wf + 128 + k);
    t[e] = acc;
    s += acc; s2 += acc*acc;
  }
  #pragma unroll
  for (int o = 32; o; o >>= 1) { s += __shfl_down(s, o); s2 += __shfl_down(s2, o); }
  __shared__ float la[4], lb[4];
  int lane = threadIdx.x & 63, wid = threadIdx.x >> 6;
  if (lane == 0) { la[wid] = s; lb[wid] = s2; }
  __syncthreads();
  if (threadIdx.x == 0) {
    atomicAdd(&gstats[0], la[0]+la[1]+la[2]+la[3]);
    atomicAdd(&gstats[1], lb[0]+lb[1]+lb[2]+lb[3]);
  }
}

// ---------------- gate part 2: e=exp(silu(bn(t))), wexp=w[src]*e, sum_w[dst]+= -----------
__global__ void gate2_kernel(const float* __restrict__ t, const float* __restrict__ gstats,
                             const float* __restrict__ gfL, const float* __restrict__ befL,
                             const float* __restrict__ nodew, const int* __restrict__ src,
                             const int* __restrict__ dst, float* __restrict__ wexp,
                             float* __restrict__ sum_w, int E, float invE) {
  float m   = gstats[0]*invE;
  float var = gstats[1]*invE - m*m;
  float sc = gfL[0]*rsqrtf(var + 1e-5f);
  float sh = befL[0] - m*sc;
  for (int e = blockIdx.x*blockDim.x + threadIdx.x; e < E; e += gridDim.x*blockDim.x) {
    float v = siluf(t[e]*sc + sh);
    float we = nodew[src[e]] * expf(v);
    wexp[e] = we;
    atomicAdd(&sum_w[dst[e]], we);
  }
}

// ---------------- z = [x_src,x_dst] @ Wg via MFMA.  PASS0: stats.  PASS1: scatter --------
template<int PASS>
__launch_bounds__(256, 2)
__global__ void zpass_kernel(const unsigned short* __restrict__ xb,
                             const int* __restrict__ src, const int* __restrict__ dst,
                             const unsigned short* __restrict__ Wgt,
                             const float* __restrict__ bg,
                             float* __restrict__ zstats,
                             const float* __restrict__ gg, const float* __restrict__ beg,
                             const float* __restrict__ wexp, const float* __restrict__ sum_w,
                             float* __restrict__ h, int E, float invE) {
  // Wgt staged in LDS, 16B slots XOR-swizzled by row&7 to break the stride-512B conflict
  __shared__ unsigned short wlds[128*256];
  for (int i = threadIdx.x; i < 128*32; i += 256) {
    int row = i >> 5, slot = i & 31;
    int phys = slot ^ (row & 7);
    *(uint4*)(&wlds[(row << 8) + (phys << 3)]) = *(const uint4*)(Wgt + (row << 8) + (slot << 3));
  }
  __syncthreads();

  const int lane = threadIdx.x & 63;
  const int wid  = threadIdx.x >> 6;
  const int l15  = lane & 15;
  const int l4   = lane >> 4;

  float bgv[8];
  float zmean[8], zinv[8], ggv[8], begv[8];
  #pragma unroll
  for (int ct = 0; ct < 8; ++ct) {
    int f = ct*16 + l15;
    bgv[ct] = bg[f];
    if (PASS == 1) {
      float m = zstats[f] * invE;
      float v = zstats[128+f] * invE - m*m;
      zmean[ct] = m;
      zinv[ct]  = rsqrtf(v + 1e-5f);
      ggv[ct]   = gg[f];
      begv[ct]  = beg[f];
    }
  }
  float zs[8]  = {0,0,0,0,0,0,0,0};
  float zs2[8] = {0,0,0,0,0,0,0,0};

  const int ntiles = (E + 63) >> 6;
  for (int tt = blockIdx.x; tt < ntiles; tt += gridDim.x) {
    const int ebase = tt*64 + wid*16;
    int er = ebase + l15;
    int ec = er < E ? er : E - 1;
    const unsigned short* pS = xb + ((size_t)src[ec] << 7);
    const unsigned short* pD = xb + ((size_t)dst[ec] << 7);

    f32x4 acc[8];
    #pragma unroll
    for (int ct = 0; ct < 8; ++ct) { f32x4 z4 = {0.f,0.f,0.f,0.f}; acc[ct] = z4; }

    #pragma unroll
    for (int kk = 0; kk < 8; ++kk) {
      const unsigned short* pa = (kk < 4 ? pS : pD) + ((kk & 3) << 5) + (l4 << 3);
      short8 afrag = *(const short8*)pa;
      #pragma unroll
      for (int ct = 0; ct < 8; ++ct) {
        int n = ct*16 + l15;
        int slot = ((kk << 2) + l4) ^ (n & 7);
        short8 bfrag = *(const short8*)(&wlds[(n << 8) + (slot << 3)]);
        acc[ct] = __builtin_amdgcn_mfma_f32_16x16x32_bf16(afrag, bfrag, acc[ct], 0, 0, 0);
      }
    }

    if (PASS == 0) {
      #pragma unroll
      for (int ct = 0; ct < 8; ++ct) {
        #pragma unroll
        for (int j = 0; j < 4; ++j) {
          int e2 = ebase + l4*4 + j;
          if (e2 < E) {
            float v = acc[ct][j] + bgv[ct];
            zs[ct] += v; zs2[ct] += v*v;
          }
        }
      }
    } else {
      #pragma unroll
      for (int j = 0; j < 4; ++j) {
        int e2 = ebase + l4*4 + j;
        if (e2 < E) {
          int dn = dst[e2];
          float a = wexp[e2] / sum_w[dn];
          float* hrow = h + ((size_t)dn << 7);
          #pragma unroll
          for (int ct = 0; ct < 8; ++ct) {
            float v = acc[ct][j] + bgv[ct];
            v = (v - zmean[ct]) * zinv[ct] * ggv[ct] + begv[ct];
            v = siluf(v);
            atomicAdd(hrow + ct*16 + l15, a * v);
          }
        }
      }
    }
  }

  if (PASS == 0) {
    #pragma unroll
    for (int ct = 0; ct < 8; ++ct) {
      zs[ct]  += __shfl_xor(zs[ct], 16);  zs[ct]  += __shfl_xor(zs[ct], 32);
      zs2[ct] += __shfl_xor(zs2[ct], 16); zs2[ct] += __shfl_xor(zs2[ct], 32);
    }
    __syncthreads();                 // done with wlds as weights; reuse as reduce scratch
    float* red = (float*)wlds;
    if (l4 == 0) {
      #pragma unroll
      for (int ct = 0; ct < 8; ++ct) {
        red[(wid*8 + ct)*16 + l15]       = zs[ct];
        red[512 + (wid*8 + ct)*16 + l15] = zs2[ct];
      }
    }
    __syncthreads();
    if (threadIdx.x < 128) {
      int f = threadIdx.x, ct = f >> 4, ll = f & 15;
      float s = 0, s2 = 0;
      #pragma unroll
      for (int ww = 0; ww < 4; ++ww) {
        s  += red[(ww*8 + ct)*16 + ll];
        s2 += red[512 + (ww*8 + ct)*16 + ll];
      }
      atomicAdd(&zstats[f],       s);
      atomicAdd(&zstats[128 + f], s2);
    }
  }
}

// ---------------- reparameterize + kld accumulation --------------------------------------
__global__ void reparam_kernel(const float* __restrict__ mu, const float* __restrict__ lv,
                               const float* __restrict__ eps, float* __restrict__ x,
                               unsigned short* __restrict__ xb, float* __restrict__ kacc,
                               size_t total) {
  float part = 0;
  for (size_t i = (size_t)blockIdx.x*blockDim.x + threadIdx.x; i < total;
       i += (size_t)gridDim.x*blockDim.x) {
    float m = mu[i], l = lv[i];
    float el = expf(l);
    float v = eps[i]*expf(0.5f*l) + m;
    x[i] = v;
    xb[i] = f2bf(v);
    part += 1.f + l - m*m - el;
  }
  #pragma unroll
  for (int o = 32; o; o >>= 1) part += __shfl_down(part, o);
  __shared__ float la[4];
  int lane = threadIdx.x & 63, wid = threadIdx.x >> 6;
  if (lane == 0) la[wid] = part;
  __syncthreads();
  if (threadIdx.x == 0) atomicAdd(kacc, la[0]+la[1]+la[2]+la[3]);
}

// ---------------- pooling ----------------------------------------------------------------
__global__ void pool_kernel(const float* __restrict__ x, const int* __restrict__ gid,
                            float* __restrict__ pools, float* __restrict__ cnt, size_t total) {
  for (size_t i = (size_t)blockIdx.x*blockDim.x + threadIdx.x; i < total;
       i += (size_t)gridDim.x*blockDim.x) {
    int n = (int)(i >> 7), f = (int)(i & 127);
    int g = gid[n];
    atomicAdd(&pools[(size_t)g*128 + f], x[i]);
    if (f == 0) atomicAdd(&cnt[g], 1.f);
  }
}

__global__ void finalize_kernel(const float* __restrict__ pools, const float* __restrict__ cnt,
                                const float* __restrict__ kacc, float* __restrict__ out,
                                int NG, float invN) {
  int i = blockIdx.x*blockDim.x + threadIdx.x;
  if (i < NG*128) {
    float c = cnt[i >> 7];
    c = c > 1.f ? c : 1.f;
    out[i] = pools[i] / c;
  }
  if (i == 0) out[NG*128] = -0.5f * kacc[0] * invN;
}

// =========================================================================================
extern "C" void kernel_launch(void* const* d_in, const int* in_sizes, int n_in,
                              void* d_out, int out_size, void* d_ws, size_t ws_size,
                              hipStream_t stream) {
  const float* atom    = (const float*)d_in[0];
  const float* nodew   = (const float*)d_in[1];
  const float* epsp    = (const float*)d_in[2];
  const int*   src     = (const int*)d_in[3];
  const int*   dst     = (const int*)d_in[4];
  const int*   gid     = (const int*)d_in[5];
  const float* W_embed = (const float*)d_in[6];
  const float* b_embed = (const float*)d_in[7];
  const float* g_embed = (const float*)d_in[8];
  const float* be_embed= (const float*)d_in[9];
  const float* Wf      = (const float*)d_in[10];
  const float* bfp     = (const float*)d_in[11];
  const float* gfp     = (const float*)d_in[12];
  const float* befp    = (const float*)d_in[13];
  const float* Wg      = (const float*)d_in[14];
  const float* bg      = (const float*)d_in[15];
  const float* gg      = (const float*)d_in[16];
  const float* beg     = (const float*)d_in[17];
  const float* gn      = (const float*)d_in[18];
  const float* ben     = (const float*)d_in[19];
  const float* W_mu    = (const float*)d_in[20];
  const float* b_mu    = (const float*)d_in[21];
  const float* W_var   = (const float*)d_in[22];
  const float* b_var   = (const float*)d_in[23];

  const int N   = in_sizes[1];
  const int E   = in_sizes[3];
  const int AIN = in_sizes[0] / N;
  const int NG  = (out_size - 1) / HID;

  char* w = (char*)d_ws;
  size_t off = 0;
  auto alloc = [&](size_t bytes) { size_t r = off; off = (off + bytes + 255) & ~(size_t)255; return r; };
  size_t o_x    = alloc((size_t)N*HID*4);
  size_t o_xb   = alloc((size_t)N*HID*2);
  size_t o_mu   = alloc((size_t)N*HID*4);
  size_t o_lv   = alloc((size_t)N*HID*4);
  size_t o_t    = alloc((size_t)E*4);
  size_t o_wexp = alloc((size_t)E*4);
  size_t o_sw   = alloc((size_t)N*4);        // sum_w ...
  size_t o_h    = alloc((size_t)N*HID*4);    // ... h adjacent (single memset)
  size_t o_wgt  = alloc((size_t)128*256*2);
  size_t o_st   = alloc(514*4);              // [0:2) gate stats, [2:258) z stats, [258:514) node stats
  size_t o_kp   = alloc((size_t)(64 + NG*HID + NG)*4);

  float* x              = (float*)(w + o_x);
  unsigned short* xb    = (unsigned short*)(w + o_xb);
  float* mu             = (float*)(w + o_mu);
  float* lv             = (float*)(w + o_lv);
  float* tbuf           = (float*)(w + o_t);
  float* wexp           = (float*)(w + o_wexp);
  float* sum_w          = (float*)(w + o_sw);
  float* h              = (float*)(w + o_h);
  unsigned short* Wgt   = (unsigned short*)(w + o_wgt);
  float* stats          = (float*)(w + o_st);
  float* gstats         = stats;
  float* zstats         = stats + 2;
  float* nstats         = stats + 258;
  float* kacc           = (float*)(w + o_kp);
  float* pools          = kacc + 64;
  float* cnt            = pools + (size_t)NG*HID;

  const size_t swh_bytes = (o_h + (size_t)N*HID*4) - o_sw;
  const dim3 B(256);
  const int mblk = (N + 63) / 64;
  const float invN = 1.f / (float)N;
  const float invE = 1.f / (float)E;
  const size_t totalNH = (size_t)N * HID;

  // ---- zero accumulators used across the call ----
  hipMemsetAsync(w + o_st, 0, 514*4, stream);
  hipMemsetAsync(w + o_kp, 0, (64 + (size_t)NG*HID + NG)*4, stream);

  // ---- atom embedding: x = silu(bn(atom @ W_embed + b)) ----
  gemm_f32_kernel<<<dim3(mblk), B, 0, stream>>>(atom, W_embed, b_embed, h, N, AIN);
  colstats_kernel<<<dim3(512), B, 0, stream>>>(h, N, nstats);
  bn_act_kernel<true,false><<<dim3(2048), B, 0, stream>>>(h, nstats, g_embed, be_embed,
                                                          x, invN, x, xb, totalNH);

  for (int l = 0; l < LAYERS; ++l) {
    if (l == 1) {  // after NBASE=1 base layers: reparameterize
      gemm_f32_kernel<<<dim3(mblk), B, 0, stream>>>(x, W_mu,  b_mu,  mu, N, HID);
      gemm_f32_kernel<<<dim3(mblk), B, 0, stream>>>(x, W_var, b_var, lv, N, HID);
      reparam_kernel<<<dim3(2048), B, 0, stream>>>(mu, lv, epsp, x, xb, kacc, totalNH);
    }
    wgt_prep_kernel<<<dim3(128), B, 0, stream>>>(Wg + (size_t)l*4*256*32, Wgt);
    hipMemsetAsync(w + o_st, 0, 514*4, stream);
    hipMemsetAsync(w + o_sw, 0, swh_bytes, stream);  // sum_w + h
    gate1_kernel<<<dim3(1024), B, 0, stream>>>(xb, src, dst, Wf + l*256, bfp + l,
                                               tbuf, gstats, E);
    gate2_kernel<<<dim3(1024), B, 0, stream>>>(tbuf, gstats, gfp + l, befp + l, nodew,
                                               src, dst, wexp, sum_w, E, invE);
    zpass_kernel<0><<<dim3(1024), B, 0, stream>>>(xb, src, dst, Wgt, bg + l*128, zstats,
                                                  nullptr, nullptr, nullptr, nullptr,
                                                  nullptr, E, invE);
    zpass_kernel<1><<<dim3(1024), B, 0, stream>>>(xb, src, dst, Wgt, bg + l*128, zstats,
                                                  gg + l*128, beg + l*128, wexp, sum_w,
                                                  h, E, invE);
    colstats_kernel<<<dim3(512), B, 0, stream>>>(h, N, nstats);
    bn_act_kernel<false,true><<<dim3(2048), B, 0, stream>>>(h, nstats, gn + l*128, ben + l*128,
                                                            x, invN, x, xb, totalNH);
  }

  // ---- pooling + output ----
  pool_kernel<<<dim3(1024), B, 0, stream>>>(x, gid, pools, cnt, totalNH);
  finalize_kernel<<<dim3((NG*HID + 255)/256), B, 0, stream>>>(pools, cnt, kacc,
                                                              (float*)d_out, NG, invN);
}

// Round 4
// 3258.426 us; speedup vs baseline: 1.8130x; 1.8130x over previous
//
#include <hip/hip_runtime.h>
#include <hip/hip_bf16.h>
#include <stdint.h>

#define HID 128
#define LAYERS 5

typedef __attribute__((ext_vector_type(8))) short short8;
typedef __attribute__((ext_vector_type(4))) float f32x4;

__device__ __forceinline__ float bf2f(unsigned int u16) {
  union { unsigned int i; float f; } c; c.i = u16 << 16; return c.f;
}
__device__ __forceinline__ unsigned short f2bf(float f) {
  union { float f; unsigned int i; } c; c.f = f;
  unsigned int r = c.i + 0x7fffu + ((c.i >> 16) & 1u);
  return (unsigned short)(r >> 16);
}
__device__ __forceinline__ float siluf(float v) { return v / (1.f + expf(-v)); }

// ---------------- f32 GEMM (embed only): out[M,128] = A[M,K] @ W[K,128] + bias -----------
__global__ void gemm_f32_kernel(const float* __restrict__ A, const float* __restrict__ W,
                                const float* __restrict__ bias, float* __restrict__ out,
                                int M, int K) {
  __shared__ float As[64][33];
  __shared__ float Bs[32][132];
  int tx = threadIdx.x & 15;
  int ty = threadIdx.x >> 4;
  int row0 = blockIdx.x * 64;
  float acc[4][8] = {};
  for (int k0 = 0; k0 < K; k0 += 32) {
    for (int i = threadIdx.x; i < 64*32; i += 256) {
      int r = i >> 5, c = i & 31;
      int gr = row0 + r, gc = k0 + c;
      As[r][c] = (gr < M && gc < K) ? A[(size_t)gr*K + gc] : 0.f;
    }
    for (int i = threadIdx.x; i < 32*128; i += 256) {
      int r = i >> 7, c = i & 127;
      int gk = k0 + r;
      Bs[r][c] = (gk < K) ? W[(size_t)gk*128 + c] : 0.f;
    }
    __syncthreads();
    #pragma unroll 8
    for (int k = 0; k < 32; ++k) {
      float a[4], b[8];
      #pragma unroll
      for (int i = 0; i < 4; ++i) a[i] = As[ty*4+i][k];
      #pragma unroll
      for (int j = 0; j < 8; ++j) b[j] = Bs[k][tx*8+j];
      #pragma unroll
      for (int i = 0; i < 4; ++i)
        #pragma unroll
        for (int j = 0; j < 8; ++j) acc[i][j] += a[i]*b[j];
    }
    __syncthreads();
  }
  #pragma unroll
  for (int i = 0; i < 4; ++i) {
    int gr = row0 + ty*4 + i;
    if (gr < M) {
      #pragma unroll
      for (int j = 0; j < 8; ++j)
        out[(size_t)gr*128 + tx*8 + j] = acc[i][j] + bias[tx*8 + j];
    }
  }
}

// ---------------- per-feature sum/sumsq over rows (embed BN stats) -----------------------
__global__ void colstats_kernel(const float* __restrict__ in, int M, float* __restrict__ stats) {
  int f = threadIdx.x & 127;
  int rl = threadIdx.x >> 7;
  float s = 0, s2 = 0;
  for (int r = blockIdx.x*2 + rl; r < M; r += gridDim.x*2) {
    float v = in[(size_t)r*128 + f];
    s += v; s2 += v*v;
  }
  __shared__ float l1[256], l2[256];
  l1[threadIdx.x] = s; l2[threadIdx.x] = s2;
  __syncthreads();
  if (rl == 0) {
    atomicAdd(&stats[f],     s  + l1[128+f]);
    atomicAdd(&stats[128+f], s2 + l2[128+f]);
  }
}

// ---------------- BN (+silu / +residual), writes f32 x and bf16 xb -----------------------
template<bool SILU, bool RES>
__global__ void bn_act_kernel(const float* __restrict__ in, const float* __restrict__ stats,
                              const float* __restrict__ g, const float* __restrict__ be,
                              const float* __restrict__ resid, float invM,
                              float* __restrict__ xout, unsigned short* __restrict__ xbout,
                              size_t total) {
  int f = threadIdx.x & 127;
  float mean = stats[f] * invM;
  float var  = stats[128+f] * invM - mean*mean;
  float sc = g[f] * rsqrtf(var + 1e-5f);
  float sh = be[f] - mean * sc;
  for (size_t i = (size_t)blockIdx.x*blockDim.x + threadIdx.x; i < total;
       i += (size_t)gridDim.x*blockDim.x) {
    float v = in[i]*sc + sh;
    if (SILU) v = siluf(v);
    if (RES)  v += resid[i];
    xout[i] = v;
    xbout[i] = f2bf(v);
  }
}

// ---------------- CSR build: histogram, scan, scatter ------------------------------------
__global__ void hist_kernel(const int* __restrict__ dst, int* __restrict__ indeg, int E) {
  for (int e = blockIdx.x*blockDim.x + threadIdx.x; e < E; e += gridDim.x*blockDim.x)
    atomicAdd(&indeg[dst[e]], 1);
}

__global__ void scan_block_kernel(const int* __restrict__ in, int n,
                                  int* __restrict__ excl, int* __restrict__ totals) {
  __shared__ int tmp[256];
  int idx = blockIdx.x*256 + threadIdx.x;
  int v = (idx < n) ? in[idx] : 0;
  tmp[threadIdx.x] = v;
  __syncthreads();
  for (int o = 1; o < 256; o <<= 1) {
    int t = (threadIdx.x >= o) ? tmp[threadIdx.x - o] : 0;
    __syncthreads();
    tmp[threadIdx.x] += t;
    __syncthreads();
  }
  if (idx < n) excl[idx] = tmp[threadIdx.x] - v;
  if (threadIdx.x == 255 && totals) totals[blockIdx.x] = tmp[255];
}

__global__ void scan_add_kernel(const int* __restrict__ excl, const int* __restrict__ tot_excl,
                                const int* __restrict__ indeg, int* __restrict__ cstart, int n) {
  int idx = blockIdx.x*256 + threadIdx.x;
  if (idx < n) {
    int v = excl[idx] + tot_excl[blockIdx.x];
    cstart[idx] = v;
    if (idx == n-1) cstart[n] = v + indeg[idx];
  }
}

__global__ void scatter_kernel(const int* __restrict__ src, const int* __restrict__ dst,
                               const int* __restrict__ cstart, int* __restrict__ fill,
                               int* __restrict__ csrc, int E) {
  for (int e = blockIdx.x*blockDim.x + threadIdx.x; e < E; e += gridDim.x*blockDim.x) {
    int d = dst[e];
    int pos = cstart[d] + atomicAdd(&fill[d], 1);
    csrc[pos] = src[e];
  }
}

// ---------------- weight preps (bf16, B^T [col][k] layout) -------------------------------
__global__ void prep_wg_kernel(const float* __restrict__ WgL, const float* __restrict__ bgL,
                               unsigned short* __restrict__ Bt, float* __restrict__ bias) {
  int i = blockIdx.x*256 + threadIdx.x;
  if (i < 256*128) {
    int col = i >> 7, k = i & 127;
    int c = col & 127, h = c >> 5, d = c & 31;
    int krow = (col < 128) ? k : 128 + k;
    Bt[i] = f2bf(WgL[((size_t)h*256 + krow)*32 + d]);
  }
  if (i < 256) bias[i] = (i < 128) ? 0.f : bgL[i-128];
}

__global__ void prep_mv_kernel(const float* __restrict__ Wm, const float* __restrict__ Wv,
                               const float* __restrict__ bm, const float* __restrict__ bv,
                               unsigned short* __restrict__ Bt, float* __restrict__ bias) {
  int i = blockIdx.x*256 + threadIdx.x;
  if (i < 256*128) {
    int col = i >> 7, k = i & 127;
    Bt[i] = f2bf(col < 128 ? Wm[(size_t)k*128 + col] : Wv[(size_t)k*128 + col - 128]);
  }
  if (i < 256) bias[i] = (i < 128) ? bm[i] : bv[i-128];
}

// ---------------- node GEMM: C[M,256] = xb[M,128] @ Bt^T + bias (MFMA) -------------------
__launch_bounds__(256)
__global__ void uv_gemm_kernel(const unsigned short* __restrict__ xb,
                               const unsigned short* __restrict__ Bt,
                               const float* __restrict__ bias,
                               float* __restrict__ C, int M) {
  __shared__ unsigned short wlds[256*128];
  for (int i = threadIdx.x; i < 256*16; i += 256) {
    int row = i >> 4, slot = i & 15, phys = slot ^ (row & 7);
    *(uint4*)&wlds[row*128 + phys*8] = *(const uint4*)(Bt + (size_t)row*128 + slot*8);
  }
  __syncthreads();
  int lane = threadIdx.x & 63, wid = threadIdx.x >> 6;
  int l15 = lane & 15, l4 = lane >> 4;
  int n0 = blockIdx.x*64 + wid*16;
  f32x4 acc[16];
  #pragma unroll
  for (int ct = 0; ct < 16; ++ct) { f32x4 z = {0.f,0.f,0.f,0.f}; acc[ct] = z; }
  int ar = n0 + l15; if (ar >= M) ar = M - 1;
  #pragma unroll
  for (int kk = 0; kk < 4; ++kk) {
    short8 af = *(const short8*)(xb + (size_t)ar*128 + kk*32 + l4*8);
    #pragma unroll
    for (int ct = 0; ct < 16; ++ct) {
      int col = ct*16 + l15;
      int slot = (kk*4 + l4) ^ (col & 7);
      short8 bfr = *(const short8*)&wlds[col*128 + slot*8];
      acc[ct] = __builtin_amdgcn_mfma_f32_16x16x32_bf16(af, bfr, acc[ct], 0, 0, 0);
    }
  }
  #pragma unroll
  for (int ct = 0; ct < 16; ++ct) {
    int col = ct*16 + l15;
    #pragma unroll
    for (int j = 0; j < 4; ++j) {
      int n = n0 + l4*4 + j;
      if (n < M) C[(size_t)n*256 + col] = acc[ct][j] + bias[col];
    }
  }
}

// ---------------- per-node gate scalars: p = x . Wf_src ; q = x . Wf_dst + bf ------------
__global__ void pq_kernel(const float* __restrict__ x, const float* __restrict__ WfL,
                          const float* __restrict__ bfL, float* __restrict__ p,
                          float* __restrict__ q, int N) {
  __shared__ float wf[256];
  wf[threadIdx.x] = WfL[threadIdx.x];
  __syncthreads();
  int wid = threadIdx.x >> 6, lane = threadIdx.x & 63;
  float bf0 = bfL[0];
  for (int n = blockIdx.x*4 + wid; n < N; n += gridDim.x*4) {
    float2 xv = *(const float2*)(x + (size_t)n*128 + lane*2);
    float pp = xv.x*wf[lane*2]     + xv.y*wf[lane*2+1];
    float qq = xv.x*wf[128+lane*2] + xv.y*wf[129+lane*2];
    #pragma unroll
    for (int o = 32; o; o >>= 1) { pp += __shfl_down(pp, o); qq += __shfl_down(qq, o); }
    if (lane == 0) { p[n] = pp; q[n] = qq + bf0; }
  }
}

// ---------------- gate BN stats over edges: sum/sumsq of t = p[src]+q[dst] ---------------
__global__ void gstat_kernel(const float* __restrict__ p, const float* __restrict__ q,
                             const int* __restrict__ src, const int* __restrict__ dst,
                             float* __restrict__ gstats, int E) {
  float s = 0, s2 = 0;
  for (int e = blockIdx.x*blockDim.x + threadIdx.x; e < E; e += gridDim.x*blockDim.x) {
    float t = p[src[e]] + q[dst[e]];
    s += t; s2 += t*t;
  }
  #pragma unroll
  for (int o = 32; o; o >>= 1) { s += __shfl_down(s, o); s2 += __shfl_down(s2, o); }
  __shared__ float la[4], lb[4];
  int lane = threadIdx.x & 63, wid = threadIdx.x >> 6;
  if (lane == 0) { la[wid] = s; lb[wid] = s2; }
  __syncthreads();
  if (threadIdx.x == 0) {
    atomicAdd(&gstats[0], la[0]+la[1]+la[2]+la[3]);
    atomicAdd(&gstats[1], lb[0]+lb[1]+lb[2]+lb[3]);
  }
}

// ---------------- walk1: per dst node — gate apply, wexp, sum_w, z-stats -----------------
__global__ void walk1_kernel(const float* __restrict__ UV, const int* __restrict__ cs,
                             const int* __restrict__ csrc, const float* __restrict__ p,
                             const float* __restrict__ q, const float* __restrict__ nodew,
                             const float* __restrict__ gstats, const float* __restrict__ gfL,
                             const float* __restrict__ befL, float* __restrict__ wexp,
                             float* __restrict__ sum_w, float* __restrict__ zstats,
                             int N, float invE) {
  int f = threadIdx.x & 127;
  float gm = gstats[0]*invE;
  float gv = gstats[1]*invE - gm*gm;
  float gsc = gfL[0]*rsqrtf(gv + 1e-5f);
  float gsh = befL[0] - gm*gsc;
  float zs = 0, zs2 = 0;
  int g = threadIdx.x >> 7;
  for (int n = blockIdx.x*2 + g; n < N; n += gridDim.x*2) {
    float vb = UV[(size_t)n*256 + 128 + f];
    float qn = q[n];
    int s0 = cs[n], s1 = cs[n+1];
    float sw = 0;
    int sn = (s0 < s1) ? csrc[s0] : 0;
    for (int j = s0; j < s1; ++j) {
      int snn = (j+1 < s1) ? csrc[j+1] : 0;
      float u = UV[(size_t)sn*256 + f];
      float t = p[sn] + qn;
      float v = t*gsc + gsh;
      v = v / (1.f + expf(-v));
      float we = nodew[sn] * expf(v);
      if (f == 0) wexp[j] = we;
      sw += we;
      float z = u + vb;
      zs += z; zs2 += z*z;
      sn = snn;
    }
    if (f == 0) sum_w[n] = sw;
  }
  __shared__ float r1[256], r2[256];
  r1[threadIdx.x] = zs; r2[threadIdx.x] = zs2;
  __syncthreads();
  if (threadIdx.x < 128) {
    atomicAdd(&zstats[f],     r1[f] + r1[128+f]);
    atomicAdd(&zstats[128+f], r2[f] + r2[128+f]);
  }
}

// ---------------- walk2: per dst node — aggregate h[n], accumulate node BN stats ---------
__global__ void walk2_kernel(const float* __restrict__ UV, const int* __restrict__ cs,
                             const int* __restrict__ csrc, const float* __restrict__ wexp,
                             const float* __restrict__ sum_w, const float* __restrict__ zstats,
                             const float* __restrict__ gg, const float* __restrict__ beg,
                             float* __restrict__ h, float* __restrict__ nstats,
                             int N, float invE) {
  int f = threadIdx.x & 127;
  float zm = zstats[f]*invE;
  float zv = zstats[128+f]*invE - zm*zm;
  float zinv = rsqrtf(zv + 1e-5f);
  float sc = gg[f]*zinv, sh = beg[f] - zm*sc;
  float ns = 0, ns2 = 0;
  int g = threadIdx.x >> 7;
  for (int n = blockIdx.x*2 + g; n < N; n += gridDim.x*2) {
    float vb = UV[(size_t)n*256 + 128 + f];
    int s0 = cs[n], s1 = cs[n+1];
    float inv = (s1 > s0) ? 1.f / sum_w[n] : 0.f;
    float hacc = 0;
    int sn = (s0 < s1) ? csrc[s0] : 0;
    for (int j = s0; j < s1; ++j) {
      int snn = (j+1 < s1) ? csrc[j+1] : 0;
      float u = UV[(size_t)sn*256 + f];
      float a = wexp[j] * inv;
      float z = u + vb;
      float v = z*sc + sh;
      v = v / (1.f + expf(-v));
      hacc += a * v;
      sn = snn;
    }
    h[(size_t)n*128 + f] = hacc;
    ns += hacc; ns2 += hacc*hacc;
  }
  __shared__ float r1[256], r2[256];
  r1[threadIdx.x] = ns; r2[threadIdx.x] = ns2;
  __syncthreads();
  if (threadIdx.x < 128) {
    atomicAdd(&nstats[f],     r1[f] + r1[128+f]);
    atomicAdd(&nstats[128+f], r2[f] + r2[128+f]);
  }
}

// ---------------- reparameterize (reads muv=[mu|lv] packed [N,256]) + kld ----------------
__global__ void reparam_kernel(const float* __restrict__ muv, const float* __restrict__ eps,
                               float* __restrict__ x, unsigned short* __restrict__ xb,
                               float* __restrict__ kacc, size_t total) {
  float part = 0;
  for (size_t i = (size_t)blockIdx.x*blockDim.x + threadIdx.x; i < total;
       i += (size_t)gridDim.x*blockDim.x) {
    size_t n = i >> 7; int f = (int)(i & 127);
    float m = muv[n*256 + f], l = muv[n*256 + 128 + f];
    float el = expf(l);
    float v = eps[i]*expf(0.5f*l) + m;
    x[i] = v;
    xb[i] = f2bf(v);
    part += 1.f + l - m*m - el;
  }
  #pragma unroll
  for (int o = 32; o; o >>= 1) part += __shfl_down(part, o);
  __shared__ float la[4];
  int lane = threadIdx.x & 63, wid = threadIdx.x >> 6;
  if (lane == 0) la[wid] = part;
  __syncthreads();
  if (threadIdx.x == 0) atomicAdd(kacc, la[0]+la[1]+la[2]+la[3]);
}

// ---------------- pooling ----------------------------------------------------------------
__global__ void pool_kernel(const float* __restrict__ x, const int* __restrict__ gid,
                            float* __restrict__ pools, float* __restrict__ cnt, size_t total) {
  for (size_t i = (size_t)blockIdx.x*blockDim.x + threadIdx.x; i < total;
       i += (size_t)gridDim.x*blockDim.x) {
    int n = (int)(i >> 7), f = (int)(i & 127);
    int g = gid[n];
    atomicAdd(&pools[(size_t)g*128 + f], x[i]);
    if (f == 0) atomicAdd(&cnt[g], 1.f);
  }
}

__global__ void finalize_kernel(const float* __restrict__ pools, const float* __restrict__ cnt,
                                const float* __restrict__ kacc, float* __restrict__ out,
                                int NG, float invN) {
  int i = blockIdx.x*blockDim.x + threadIdx.x;
  if (i < NG*128) {
    float c = cnt[i >> 7];
    c = c > 1.f ? c : 1.f;
    out[i] = pools[i] / c;
  }
  if (i == 0) out[NG*128] = -0.5f * kacc[0] * invN;
}

// =========================================================================================
extern "C" void kernel_launch(void* const* d_in, const int* in_sizes, int n_in,
                              void* d_out, int out_size, void* d_ws, size_t ws_size,
                              hipStream_t stream) {
  const float* atom    = (const float*)d_in[0];
  const float* nodew   = (const float*)d_in[1];
  const float* epsp    = (const float*)d_in[2];
  const int*   src     = (const int*)d_in[3];
  const int*   dst     = (const int*)d_in[4];
  const int*   gid     = (const int*)d_in[5];
  const float* W_embed = (const float*)d_in[6];
  const float* b_embed = (const float*)d_in[7];
  const float* g_embed = (const float*)d_in[8];
  const float* be_embed= (const float*)d_in[9];
  const float* Wf      = (const float*)d_in[10];
  const float* bfp     = (const float*)d_in[11];
  const float* gfp     = (const float*)d_in[12];
  const float* befp    = (const float*)d_in[13];
  const float* Wg      = (const float*)d_in[14];
  const float* bg      = (const float*)d_in[15];
  const float* gg      = (const float*)d_in[16];
  const float* beg     = (const float*)d_in[17];
  const float* gn      = (const float*)d_in[18];
  const float* ben     = (const float*)d_in[19];
  const float* W_mu    = (const float*)d_in[20];
  const float* b_mu    = (const float*)d_in[21];
  const float* W_var   = (const float*)d_in[22];
  const float* b_var   = (const float*)d_in[23];

  const int N   = in_sizes[1];
  const int E   = in_sizes[3];
  const int AIN = in_sizes[0] / N;
  const int NG  = (out_size - 1) / HID;

  char* w = (char*)d_ws;
  size_t off = 0;
  auto alloc = [&](size_t bytes) { size_t r = off; off = (off + bytes + 255) & ~(size_t)255; return r; };
  size_t o_x    = alloc((size_t)N*HID*4);
  size_t o_xb   = alloc((size_t)N*HID*2);
  size_t o_uv   = alloc((size_t)N*256*4);
  size_t o_h    = alloc((size_t)N*HID*4);
  size_t o_p    = alloc((size_t)N*4);
  size_t o_q    = alloc((size_t)N*4);
  size_t o_sw   = alloc((size_t)N*4);
  size_t o_wexp = alloc((size_t)E*4);
  size_t o_csrc = alloc((size_t)E*4);
  size_t o_cs   = alloc((size_t)(N+1)*4);
  size_t o_deg  = alloc((size_t)2*N*4);      // indeg | fill (single memset)
  size_t o_excl = alloc((size_t)N*4);
  size_t o_tot  = alloc(512*4);              // totals | tot_excl
  size_t o_bt   = alloc((size_t)256*128*2);
  size_t o_bias = alloc(256*4);
  size_t o_st   = alloc(514*4);              // [0:2) gate, [2:258) z, [258:514) node stats
  size_t o_kp   = alloc((size_t)(64 + NG*HID + NG)*4);

  float* x              = (float*)(w + o_x);
  unsigned short* xb    = (unsigned short*)(w + o_xb);
  float* UV             = (float*)(w + o_uv);
  float* h              = (float*)(w + o_h);
  float* p              = (float*)(w + o_p);
  float* q              = (float*)(w + o_q);
  float* sum_w          = (float*)(w + o_sw);
  float* wexp           = (float*)(w + o_wexp);
  int*   csrc           = (int*)(w + o_csrc);
  int*   cstart         = (int*)(w + o_cs);
  int*   indeg          = (int*)(w + o_deg);
  int*   fill           = indeg + N;
  int*   excl           = (int*)(w + o_excl);
  int*   totals         = (int*)(w + o_tot);
  int*   tot_excl       = totals + 256;
  unsigned short* Bt    = (unsigned short*)(w + o_bt);
  float* bias           = (float*)(w + o_bias);
  float* stats          = (float*)(w + o_st);
  float* gstats         = stats;
  float* zstats         = stats + 2;
  float* nstats         = stats + 258;
  float* kacc           = (float*)(w + o_kp);
  float* pools          = kacc + 64;
  float* cnt            = pools + (size_t)NG*HID;

  const dim3 B(256);
  const int mblk = (N + 63) / 64;
  const int nb1  = (N + 255) / 256;
  const float invN = 1.f / (float)N;
  const float invE = 1.f / (float)E;
  const size_t totalNH = (size_t)N * HID;

  // ---- zero accumulators ----
  hipMemsetAsync(w + o_st, 0, 514*4, stream);
  hipMemsetAsync(w + o_kp, 0, (64 + (size_t)NG*HID + NG)*4, stream);
  hipMemsetAsync(w + o_deg, 0, (size_t)2*N*4, stream);

  // ---- CSR build (dst-sorted) ----
  hist_kernel<<<dim3(1024), B, 0, stream>>>(dst, indeg, E);
  scan_block_kernel<<<dim3(nb1), B, 0, stream>>>(indeg, N, excl, totals);
  scan_block_kernel<<<dim3(1), B, 0, stream>>>(totals, nb1, tot_excl, nullptr);
  scan_add_kernel<<<dim3(nb1), B, 0, stream>>>(excl, tot_excl, indeg, cstart, N);
  scatter_kernel<<<dim3(1024), B, 0, stream>>>(src, dst, cstart, fill, csrc, E);

  // ---- atom embedding: x = silu(bn(atom @ W_embed + b)) ----
  gemm_f32_kernel<<<dim3(mblk), B, 0, stream>>>(atom, W_embed, b_embed, h, N, AIN);
  colstats_kernel<<<dim3(512), B, 0, stream>>>(h, N, nstats);
  bn_act_kernel<true,false><<<dim3(2048), B, 0, stream>>>(h, nstats, g_embed, be_embed,
                                                          x, invN, x, xb, totalNH);

  for (int l = 0; l < LAYERS; ++l) {
    if (l == 1) {  // reparameterize after NBASE=1 base layers
      prep_mv_kernel<<<dim3(128), B, 0, stream>>>(W_mu, W_var, b_mu, b_var, Bt, bias);
      uv_gemm_kernel<<<dim3(mblk), B, 0, stream>>>(xb, Bt, bias, UV, N);
      reparam_kernel<<<dim3(2048), B, 0, stream>>>(UV, epsp, x, xb, kacc, totalNH);
    }
    prep_wg_kernel<<<dim3(128), B, 0, stream>>>(Wg + (size_t)l*4*256*32, bg + l*128, Bt, bias);
    hipMemsetAsync(w + o_st, 0, 514*4, stream);
    uv_gemm_kernel<<<dim3(mblk), B, 0, stream>>>(xb, Bt, bias, UV, N);
    pq_kernel<<<dim3(2048), B, 0, stream>>>(x, Wf + l*256, bfp + l, p, q, N);
    gstat_kernel<<<dim3(1024), B, 0, stream>>>(p, q, src, dst, gstats, E);
    walk1_kernel<<<dim3(2048), B, 0, stream>>>(UV, cstart, csrc, p, q, nodew, gstats,
                                               gfp + l, befp + l, wexp, sum_w, zstats,
                                               N, invE);
    walk2_kernel<<<dim3(2048), B, 0, stream>>>(UV, cstart, csrc, wexp, sum_w, zstats,
                                               gg + l*128, beg + l*128, h, nstats, N, invE);
    bn_act_kernel<false,true><<<dim3(2048), B, 0, stream>>>(h, nstats, gn + l*128, ben + l*128,
                                                            x, invN, x, xb, totalNH);
  }

  // ---- pooling + output ----
  pool_kernel<<<dim3(1024), B, 0, stream>>>(x, gid, pools, cnt, totalNH);
  finalize_kernel<<<dim3((NG*HID + 255)/256), B, 0, stream>>>(pools, cnt, kacc,
                                                              (float*)d_out, NG, invN);
}

// Round 5
// 2340.614 us; speedup vs baseline: 2.5239x; 1.3921x over previous
//
#include <hip/hip_runtime.h>
#include <hip/hip_bf16.h>
#include <stdint.h>

#define HID 128
#define LAYERS 5

typedef __attribute__((ext_vector_type(8))) short short8;
typedef __attribute__((ext_vector_type(4))) float f32x4;

__device__ __forceinline__ float bf2f(unsigned int u16) {
  union { unsigned int i; float f; } c; c.i = u16 << 16; return c.f;
}
__device__ __forceinline__ unsigned short f2bf(float f) {
  union { float f; unsigned int i; } c; c.f = f;
  unsigned int r = c.i + 0x7fffu + ((c.i >> 16) & 1u);
  return (unsigned short)(r >> 16);
}
// raw transcendentals: v_exp_f32 computes 2^x (~1ulp); expf(x)=2^(x*log2e)
__device__ __forceinline__ float fexp(float x) {
  float r; asm("v_exp_f32 %0, %1" : "=v"(r) : "v"(x * 1.44269504f)); return r;
}
__device__ __forceinline__ float frcp(float x) {
  float r; asm("v_rcp_f32 %0, %1" : "=v"(r) : "v"(x)); return r;
}
__device__ __forceinline__ float siluf(float v) { return v * frcp(1.f + fexp(-v)); }

// ---------------- bf16 MFMA GEMM: C[M, NCT*16] = A[M, KS*32] @ Bt^T + bias ---------------
// Bt layout: [col][k] (col-major weights, k contiguous). Output f32 or bf16.
template<int KS, int NCT, bool BF16OUT>
__launch_bounds__(256)
__global__ void gemm_bf16_kernel(const unsigned short* __restrict__ A,
                                 const unsigned short* __restrict__ Bt,
                                 const float* __restrict__ bias,
                                 void* __restrict__ Cv, int M) {
  constexpr int K = KS * 32;
  constexpr int SLOTS = KS * 4;            // 16B slots per col
  constexpr int SSTR = (SLOTS + 7) & ~7;   // padded so slot^7 stays in range
  __shared__ unsigned short wlds[NCT * 16 * SSTR * 8];
  for (int i = threadIdx.x; i < NCT * 16 * SLOTS; i += 256) {
    int col = i / SLOTS, slot = i % SLOTS;
    int phys = slot ^ (col & 7);
    *(uint4*)&wlds[(col * SSTR + phys) * 8] = *(const uint4*)(Bt + (size_t)col * K + slot * 8);
  }
  __syncthreads();
  int lane = threadIdx.x & 63, wid = threadIdx.x >> 6;
  int l15 = lane & 15, l4 = lane >> 4;
  int n0 = blockIdx.x * 64 + wid * 16;
  f32x4 acc[NCT];
  #pragma unroll
  for (int ct = 0; ct < NCT; ++ct) { f32x4 z = {0.f, 0.f, 0.f, 0.f}; acc[ct] = z; }
  int ar = n0 + l15; if (ar >= M) ar = M - 1;
  #pragma unroll
  for (int kk = 0; kk < KS; ++kk) {
    short8 af = *(const short8*)(A + (size_t)ar * K + kk * 32 + l4 * 8);
    #pragma unroll
    for (int ct = 0; ct < NCT; ++ct) {
      int col = ct * 16 + l15;
      int phys = (kk * 4 + l4) ^ (col & 7);
      short8 bfr = *(const short8*)&wlds[(col * SSTR + phys) * 8];
      acc[ct] = __builtin_amdgcn_mfma_f32_16x16x32_bf16(af, bfr, acc[ct], 0, 0, 0);
    }
  }
  #pragma unroll
  for (int ct = 0; ct < NCT; ++ct) {
    int col = ct * 16 + l15;
    #pragma unroll
    for (int j = 0; j < 4; ++j) {
      int n = n0 + l4 * 4 + j;
      if (n < M) {
        float v = acc[ct][j] + bias[col];
        if (BF16OUT) ((unsigned short*)Cv)[(size_t)n * (NCT * 16) + col] = f2bf(v);
        else         ((float*)Cv)[(size_t)n * (NCT * 16) + col] = v;
      }
    }
  }
}

// ---------------- embed input/weight casts (pad K to 224) --------------------------------
__global__ void cast_atom_kernel(const float* __restrict__ atom, unsigned short* __restrict__ ab,
                                 int N, int AIN) {
  int n = blockIdx.x, k = threadIdx.x;
  if (n < N && k < 224)
    ab[(size_t)n * 224 + k] = f2bf(k < AIN ? atom[(size_t)n * AIN + k] : 0.f);
}
__global__ void prep_we_kernel(const float* __restrict__ W, unsigned short* __restrict__ Bt,
                               int AIN) {
  int i = blockIdx.x * 256 + threadIdx.x;
  if (i >= 128 * 224) return;
  int col = i / 224, k = i % 224;
  Bt[i] = f2bf(k < AIN ? W[(size_t)k * 128 + col] : 0.f);
}

// ---------------- per-feature sum/sumsq over rows (embed BN stats) -----------------------
__global__ void colstats_kernel(const float* __restrict__ in, int M, float* __restrict__ stats) {
  int f = threadIdx.x & 127;
  int rl = threadIdx.x >> 7;
  float s = 0, s2 = 0;
  for (int r = blockIdx.x * 2 + rl; r < M; r += gridDim.x * 2) {
    float v = in[(size_t)r * 128 + f];
    s += v; s2 += v * v;
  }
  __shared__ float l1[256], l2[256];
  l1[threadIdx.x] = s; l2[threadIdx.x] = s2;
  __syncthreads();
  if (rl == 0) {
    atomicAdd(&stats[f],       s  + l1[128 + f]);
    atomicAdd(&stats[128 + f], s2 + l2[128 + f]);
  }
}

// ---------------- BN (+silu / +residual), writes f32 x and bf16 xb -----------------------
template<bool SILU, bool RES>
__global__ void bn_act_kernel(const float* __restrict__ in, const float* __restrict__ stats,
                              const float* __restrict__ g, const float* __restrict__ be,
                              const float* __restrict__ resid, float invM,
                              float* __restrict__ xout, unsigned short* __restrict__ xbout,
                              size_t total) {
  int f = threadIdx.x & 127;
  float mean = stats[f] * invM;
  float var  = stats[128 + f] * invM - mean * mean;
  float sc = g[f] * rsqrtf(var + 1e-5f);
  float sh = be[f] - mean * sc;
  for (size_t i = (size_t)blockIdx.x * blockDim.x + threadIdx.x; i < total;
       i += (size_t)gridDim.x * blockDim.x) {
    float v = in[i] * sc + sh;
    if (SILU) v = siluf(v);
    if (RES)  v += resid[i];
    xout[i] = v;
    xbout[i] = f2bf(v);
  }
}

// ---------------- CSR build: histogram, scan, scatter ------------------------------------
__global__ void hist_kernel(const int* __restrict__ dst, int* __restrict__ indeg, int E) {
  for (int e = blockIdx.x * blockDim.x + threadIdx.x; e < E; e += gridDim.x * blockDim.x)
    atomicAdd(&indeg[dst[e]], 1);
}

__global__ void scan_block_kernel(const int* __restrict__ in, int n,
                                  int* __restrict__ excl, int* __restrict__ totals) {
  __shared__ int tmp[256];
  int idx = blockIdx.x * 256 + threadIdx.x;
  int v = (idx < n) ? in[idx] : 0;
  tmp[threadIdx.x] = v;
  __syncthreads();
  for (int o = 1; o < 256; o <<= 1) {
    int t = (threadIdx.x >= o) ? tmp[threadIdx.x - o] : 0;
    __syncthreads();
    tmp[threadIdx.x] += t;
    __syncthreads();
  }
  if (idx < n) excl[idx] = tmp[threadIdx.x] - v;
  if (threadIdx.x == 255 && totals) totals[blockIdx.x] = tmp[255];
}

__global__ void scan_add_kernel(const int* __restrict__ excl, const int* __restrict__ tot_excl,
                                const int* __restrict__ indeg, int* __restrict__ cstart, int n) {
  int idx = blockIdx.x * 256 + threadIdx.x;
  if (idx < n) {
    int v = excl[idx] + tot_excl[blockIdx.x];
    cstart[idx] = v;
    if (idx == n - 1) cstart[n] = v + indeg[idx];
  }
}

__global__ void scatter_kernel(const int* __restrict__ src, const int* __restrict__ dst,
                               const int* __restrict__ cstart, int* __restrict__ fill,
                               int* __restrict__ csrc, int E) {
  for (int e = blockIdx.x * blockDim.x + threadIdx.x; e < E; e += gridDim.x * blockDim.x) {
    int d = dst[e];
    int pos = cstart[d] + atomicAdd(&fill[d], 1);
    csrc[pos] = src[e];
  }
}

// ---------------- weight preps (bf16, [col][k] layout) -----------------------------------
__global__ void prep_wg_kernel(const float* __restrict__ WgL, const float* __restrict__ bgL,
                               unsigned short* __restrict__ Bt, float* __restrict__ bias) {
  int i = blockIdx.x * 256 + threadIdx.x;
  if (i < 256 * 128) {
    int col = i >> 7, k = i & 127;
    int c = col & 127, h = c >> 5, d = c & 31;
    int krow = (col < 128) ? k : 128 + k;
    Bt[i] = f2bf(WgL[((size_t)h * 256 + krow) * 32 + d]);
  }
  if (i < 256) bias[i] = (i < 128) ? 0.f : bgL[i - 128];
}

__global__ void prep_mv_kernel(const float* __restrict__ Wm, const float* __restrict__ Wv,
                               const float* __restrict__ bm, const float* __restrict__ bv,
                               unsigned short* __restrict__ Bt, float* __restrict__ bias) {
  int i = blockIdx.x * 256 + threadIdx.x;
  if (i < 256 * 128) {
    int col = i >> 7, k = i & 127;
    Bt[i] = f2bf(col < 128 ? Wm[(size_t)k * 128 + col] : Wv[(size_t)k * 128 + col - 128]);
  }
  if (i < 256) bias[i] = (i < 128) ? bm[i] : bv[i - 128];
}

// ---------------- per-node gate scalars: p = x . Wf_src ; q = x . Wf_dst + bf ------------
__global__ void pq_kernel(const float* __restrict__ x, const float* __restrict__ WfL,
                          const float* __restrict__ bfL, float* __restrict__ p,
                          float* __restrict__ q, int N) {
  __shared__ float wf[256];
  wf[threadIdx.x] = WfL[threadIdx.x];
  __syncthreads();
  int wid = threadIdx.x >> 6, lane = threadIdx.x & 63;
  float bf0 = bfL[0];
  for (int n = blockIdx.x * 4 + wid; n < N; n += gridDim.x * 4) {
    float2 xv = *(const float2*)(x + (size_t)n * 128 + lane * 2);
    float pp = xv.x * wf[lane * 2]       + xv.y * wf[lane * 2 + 1];
    float qq = xv.x * wf[128 + lane * 2] + xv.y * wf[129 + lane * 2];
    #pragma unroll
    for (int o = 32; o; o >>= 1) { pp += __shfl_down(pp, o); qq += __shfl_down(qq, o); }
    if (lane == 0) { p[n] = pp; q[n] = qq + bf0; }
  }
}

// ---------------- gate BN stats over edges: sum/sumsq of t = p[src]+q[dst] ---------------
__global__ void gstat_kernel(const float* __restrict__ p, const float* __restrict__ q,
                             const int* __restrict__ src, const int* __restrict__ dst,
                             float* __restrict__ gstats, int E) {
  float s = 0, s2 = 0;
  for (int e = blockIdx.x * blockDim.x + threadIdx.x; e < E; e += gridDim.x * blockDim.x) {
    float t = p[src[e]] + q[dst[e]];
    s += t; s2 += t * t;
  }
  #pragma unroll
  for (int o = 32; o; o >>= 1) { s += __shfl_down(s, o); s2 += __shfl_down(s2, o); }
  __shared__ float la[4], lb[4];
  int lane = threadIdx.x & 63, wid = threadIdx.x >> 6;
  if (lane == 0) { la[wid] = s; lb[wid] = s2; }
  __syncthreads();
  if (threadIdx.x == 0) {
    atomicAdd(&gstats[0], la[0] + la[1] + la[2] + la[3]);
    atomicAdd(&gstats[1], lb[0] + lb[1] + lb[2] + lb[3]);
  }
}

// ---------------- gate apply per node (thread/node): wexp[j], sum_w[n] -------------------
__global__ void gate_wexp_kernel(const int* __restrict__ cs, const int* __restrict__ csrc,
                                 const float* __restrict__ p, const float* __restrict__ q,
                                 const float* __restrict__ nodew, const float* __restrict__ gstats,
                                 const float* __restrict__ gfL, const float* __restrict__ befL,
                                 float* __restrict__ wexp, float* __restrict__ sum_w,
                                 int N, float invE) {
  float gm  = gstats[0] * invE;
  float gv  = gstats[1] * invE - gm * gm;
  float gsc = gfL[0] * rsqrtf(gv + 1e-5f);
  float gsh = befL[0] - gm * gsc;
  for (int n = blockIdx.x * blockDim.x + threadIdx.x; n < N; n += gridDim.x * blockDim.x) {
    float qn = q[n] * gsc + gsh;           // v = p*gsc + (q*gsc+gsh)
    int s0 = cs[n], s1 = cs[n + 1];
    float sw = 0;
    for (int j = s0; j < s1; ++j) {
      int sn = csrc[j];
      float v = p[sn] * gsc + qn;
      v = v * frcp(1.f + fexp(-v));        // silu
      float we = nodew[sn] * fexp(v);
      wexp[j] = we;
      sw += we;
    }
    sum_w[n] = sw;
  }
}

// ---------------- z BN stats: wave/node, 2 bf16 feats/lane; factored over U --------------
__global__ void zstat_kernel(const unsigned short* __restrict__ UVb, const int* __restrict__ cs,
                             const int* __restrict__ csrc, float* __restrict__ zstats, int N) {
  int lane = threadIdx.x & 63, wid = threadIdx.x >> 6;
  int f0 = lane * 2;
  float zs0 = 0, zq0 = 0, zs1 = 0, zq1 = 0;
  for (int n = blockIdx.x * 4 + wid; n < N; n += gridDim.x * 4) {
    unsigned vbp = *(const unsigned*)(UVb + ((size_t)n << 8) + 128 + f0);
    float vb0 = bf2f(vbp & 0xffffu), vb1 = bf2f(vbp >> 16);
    int s0 = cs[n], s1 = cs[n + 1];
    float su0 = 0, sq0 = 0, su1 = 0, sq1 = 0;
    for (int j = s0; j < s1; ++j) {
      int sn = csrc[j];
      unsigned up = *(const unsigned*)(UVb + ((size_t)sn << 8) + f0);
      float u0 = bf2f(up & 0xffffu), u1 = bf2f(up >> 16);
      su0 += u0; sq0 += u0 * u0;
      su1 += u1; sq1 += u1 * u1;
    }
    float deg = (float)(s1 - s0);
    zs0 += su0 + deg * vb0;  zq0 += sq0 + 2.f * vb0 * su0 + deg * vb0 * vb0;
    zs1 += su1 + deg * vb1;  zq1 += sq1 + 2.f * vb1 * su1 + deg * vb1 * vb1;
  }
  __shared__ float r1[4][128], r2[4][128];
  r1[wid][f0] = zs0; r1[wid][f0 + 1] = zs1;
  r2[wid][f0] = zq0; r2[wid][f0 + 1] = zq1;
  __syncthreads();
  if (threadIdx.x < 128) {
    int f = threadIdx.x;
    atomicAdd(&zstats[f],       r1[0][f] + r1[1][f] + r1[2][f] + r1[3][f]);
    atomicAdd(&zstats[128 + f], r2[0][f] + r2[1][f] + r2[2][f] + r2[3][f]);
  }
}

// ---------------- aggregate: wave/node, 2 feats/lane — h[n] + node BN stats --------------
__global__ void walk2_kernel(const unsigned short* __restrict__ UVb, const int* __restrict__ cs,
                             const int* __restrict__ csrc, const float* __restrict__ wexp,
                             const float* __restrict__ sum_w, const float* __restrict__ zstats,
                             const float* __restrict__ gg, const float* __restrict__ beg,
                             float* __restrict__ h, float* __restrict__ nstats,
                             int N, float invE) {
  int lane = threadIdx.x & 63, wid = threadIdx.x >> 6;
  int f0 = lane * 2, f1 = f0 + 1;
  float zm0 = zstats[f0] * invE, zv0 = zstats[128 + f0] * invE - zm0 * zm0;
  float sc0 = gg[f0] * rsqrtf(zv0 + 1e-5f), sh0 = beg[f0] - zm0 * sc0;
  float zm1 = zstats[f1] * invE, zv1 = zstats[128 + f1] * invE - zm1 * zm1;
  float sc1 = gg[f1] * rsqrtf(zv1 + 1e-5f), sh1 = beg[f1] - zm1 * sc1;
  float ns0 = 0, nq0 = 0, ns1 = 0, nq1 = 0;
  for (int n = blockIdx.x * 4 + wid; n < N; n += gridDim.x * 4) {
    unsigned vbp = *(const unsigned*)(UVb + ((size_t)n << 8) + 128 + f0);
    float c0 = sc0 * bf2f(vbp & 0xffffu) + sh0;
    float c1 = sc1 * bf2f(vbp >> 16)     + sh1;
    int s0 = cs[n], s1 = cs[n + 1];
    float inv = (s1 > s0) ? frcp(sum_w[n]) : 0.f;
    float h0 = 0, h1 = 0;
    for (int j = s0; j < s1; ++j) {
      int sn = csrc[j];
      unsigned up = *(const unsigned*)(UVb + ((size_t)sn << 8) + f0);
      float a = wexp[j];
      float v0 = sc0 * bf2f(up & 0xffffu) + c0;
      float v1 = sc1 * bf2f(up >> 16)     + c1;
      v0 = v0 * frcp(1.f + fexp(-v0));
      v1 = v1 * frcp(1.f + fexp(-v1));
      h0 += a * v0; h1 += a * v1;
    }
    h0 *= inv; h1 *= inv;
    *(float2*)(h + ((size_t)n << 7) + f0) = make_float2(h0, h1);
    ns0 += h0; nq0 += h0 * h0;
    ns1 += h1; nq1 += h1 * h1;
  }
  __shared__ float r1[4][128], r2[4][128];
  r1[wid][f0] = ns0; r1[wid][f1] = ns1;
  r2[wid][f0] = nq0; r2[wid][f1] = nq1;
  __syncthreads();
  if (threadIdx.x < 128) {
    int f = threadIdx.x;
    atomicAdd(&nstats[f],       r1[0][f] + r1[1][f] + r1[2][f] + r1[3][f]);
    atomicAdd(&nstats[128 + f], r2[0][f] + r2[1][f] + r2[2][f] + r2[3][f]);
  }
}

// ---------------- reparameterize (bf16 muv=[mu|lv] packed [N,256]) + kld -----------------
__global__ void reparam_kernel(const unsigned short* __restrict__ muv,
                               const float* __restrict__ eps,
                               float* __restrict__ x, unsigned short* __restrict__ xb,
                               float* __restrict__ kacc, size_t total) {
  float part = 0;
  for (size_t i = (size_t)blockIdx.x * blockDim.x + threadIdx.x; i < total;
       i += (size_t)gridDim.x * blockDim.x) {
    size_t n = i >> 7; int f = (int)(i & 127);
    float m = bf2f(muv[(n << 8) + f]);
    float l = bf2f(muv[(n << 8) + 128 + f]);
    float el = fexp(l);
    float v = eps[i] * fexp(0.5f * l) + m;
    x[i] = v;
    xb[i] = f2bf(v);
    part += 1.f + l - m * m - el;
  }
  #pragma unroll
  for (int o = 32; o; o >>= 1) part += __shfl_down(part, o);
  __shared__ float la[4];
  int lane = threadIdx.x & 63, wid = threadIdx.x >> 6;
  if (lane == 0) la[wid] = part;
  __syncthreads();
  if (threadIdx.x == 0) atomicAdd(kacc, la[0] + la[1] + la[2] + la[3]);
}

// ---------------- pooling ----------------------------------------------------------------
__global__ void pool_kernel(const float* __restrict__ x, const int* __restrict__ gid,
                            float* __restrict__ pools, float* __restrict__ cnt, size_t total) {
  for (size_t i = (size_t)blockIdx.x * blockDim.x + threadIdx.x; i < total;
       i += (size_t)gridDim.x * blockDim.x) {
    int n = (int)(i >> 7), f = (int)(i & 127);
    int g = gid[n];
    atomicAdd(&pools[(size_t)g * 128 + f], x[i]);
    if (f == 0) atomicAdd(&cnt[g], 1.f);
  }
}

__global__ void finalize_kernel(const float* __restrict__ pools, const float* __restrict__ cnt,
                                const float* __restrict__ kacc, float* __restrict__ out,
                                int NG, float invN) {
  int i = blockIdx.x * blockDim.x + threadIdx.x;
  if (i < NG * 128) {
    float c = cnt[i >> 7];
    c = c > 1.f ? c : 1.f;
    out[i] = pools[i] / c;
  }
  if (i == 0) out[NG * 128] = -0.5f * kacc[0] * invN;
}

// =========================================================================================
extern "C" void kernel_launch(void* const* d_in, const int* in_sizes, int n_in,
                              void* d_out, int out_size, void* d_ws, size_t ws_size,
                              hipStream_t stream) {
  const float* atom    = (const float*)d_in[0];
  const float* nodew   = (const float*)d_in[1];
  const float* epsp    = (const float*)d_in[2];
  const int*   src     = (const int*)d_in[3];
  const int*   dst     = (const int*)d_in[4];
  const int*   gid     = (const int*)d_in[5];
  const float* W_embed = (const float*)d_in[6];
  const float* b_embed = (const float*)d_in[7];
  const float* g_embed = (const float*)d_in[8];
  const float* be_embed= (const float*)d_in[9];
  const float* Wf      = (const float*)d_in[10];
  const float* bfp     = (const float*)d_in[11];
  const float* gfp     = (const float*)d_in[12];
  const float* befp    = (const float*)d_in[13];
  const float* Wg      = (const float*)d_in[14];
  const float* bg      = (const float*)d_in[15];
  const float* gg      = (const float*)d_in[16];
  const float* beg     = (const float*)d_in[17];
  const float* gn      = (const float*)d_in[18];
  const float* ben     = (const float*)d_in[19];
  const float* W_mu    = (const float*)d_in[20];
  const float* b_mu    = (const float*)d_in[21];
  const float* W_var   = (const float*)d_in[22];
  const float* b_var   = (const float*)d_in[23];

  const int N   = in_sizes[1];
  const int E   = in_sizes[3];
  const int AIN = in_sizes[0] / N;
  const int NG  = (out_size - 1) / HID;

  char* w = (char*)d_ws;
  size_t off = 0;
  auto alloc = [&](size_t bytes) { size_t r = off; off = (off + bytes + 255) & ~(size_t)255; return r; };
  size_t o_x    = alloc((size_t)N*HID*4);
  size_t o_xb   = alloc((size_t)N*HID*2);
  size_t o_uvb  = alloc((size_t)N*256*2);    // bf16 [U|V] (also bf16 [mu|lv])
  size_t o_h    = alloc((size_t)N*HID*4);
  size_t o_ab   = alloc((size_t)N*224*2);    // bf16 padded atom features (embed only)
  size_t o_p    = alloc((size_t)N*4);
  size_t o_q    = alloc((size_t)N*4);
  size_t o_sw   = alloc((size_t)N*4);
  size_t o_wexp = alloc((size_t)E*4);
  size_t o_csrc = alloc((size_t)E*4);
  size_t o_cs   = alloc((size_t)(N+1)*4);
  size_t o_deg  = alloc((size_t)2*N*4);      // indeg | fill (single memset)
  size_t o_excl = alloc((size_t)N*4);
  size_t o_tot  = alloc(512*4);              // totals | tot_excl
  size_t o_bt   = alloc((size_t)256*128*2);  // >= 128*224 too
  size_t o_bias = alloc(256*4);
  size_t o_st   = alloc(514*4);              // [0:2) gate, [2:258) z, [258:514) node stats
  size_t o_kp   = alloc((size_t)(64 + NG*HID + NG)*4);

  float* x              = (float*)(w + o_x);
  unsigned short* xb    = (unsigned short*)(w + o_xb);
  unsigned short* UVb   = (unsigned short*)(w + o_uvb);
  float* h              = (float*)(w + o_h);
  unsigned short* atomb = (unsigned short*)(w + o_ab);
  float* p              = (float*)(w + o_p);
  float* q              = (float*)(w + o_q);
  float* sum_w          = (float*)(w + o_sw);
  float* wexp           = (float*)(w + o_wexp);
  int*   csrc           = (int*)(w + o_csrc);
  int*   cstart         = (int*)(w + o_cs);
  int*   indeg          = (int*)(w + o_deg);
  int*   fill           = indeg + N;
  int*   excl           = (int*)(w + o_excl);
  int*   totals         = (int*)(w + o_tot);
  int*   tot_excl       = totals + 256;
  unsigned short* Bt    = (unsigned short*)(w + o_bt);
  float* bias           = (float*)(w + o_bias);
  float* stats          = (float*)(w + o_st);
  float* gstats         = stats;
  float* zstats         = stats + 2;
  float* nstats         = stats + 258;
  float* kacc           = (float*)(w + o_kp);
  float* pools          = kacc + 64;
  float* cnt            = pools + (size_t)NG*HID;

  const dim3 B(256);
  const int mblk = (N + 63) / 64;
  const int nb1  = (N + 255) / 256;
  const float invN = 1.f / (float)N;
  const float invE = 1.f / (float)E;
  const size_t totalNH = (size_t)N * HID;

  // ---- zero accumulators ----
  hipMemsetAsync(w + o_st, 0, 514*4, stream);
  hipMemsetAsync(w + o_kp, 0, (64 + (size_t)NG*HID + NG)*4, stream);
  hipMemsetAsync(w + o_deg, 0, (size_t)2*N*4, stream);

  // ---- CSR build (dst-sorted) ----
  hist_kernel<<<dim3(1024), B, 0, stream>>>(dst, indeg, E);
  scan_block_kernel<<<dim3(nb1), B, 0, stream>>>(indeg, N, excl, totals);
  scan_block_kernel<<<dim3(1), B, 0, stream>>>(totals, nb1, tot_excl, nullptr);
  scan_add_kernel<<<dim3(nb1), B, 0, stream>>>(excl, tot_excl, indeg, cstart, N);
  scatter_kernel<<<dim3(1024), B, 0, stream>>>(src, dst, cstart, fill, csrc, E);

  // ---- atom embedding: x = silu(bn(atom @ W_embed + b)) via bf16 MFMA (K padded 224) ----
  cast_atom_kernel<<<dim3(N), B, 0, stream>>>(atom, atomb, N, AIN);
  prep_we_kernel<<<dim3(112), B, 0, stream>>>(W_embed, Bt, AIN);
  gemm_bf16_kernel<7, 8, false><<<dim3(mblk), B, 0, stream>>>(atomb, Bt, b_embed, h, N);
  colstats_kernel<<<dim3(512), B, 0, stream>>>(h, N, nstats);
  bn_act_kernel<true,false><<<dim3(2048), B, 0, stream>>>(h, nstats, g_embed, be_embed,
                                                          x, invN, x, xb, totalNH);

  for (int l = 0; l < LAYERS; ++l) {
    if (l == 1) {  // reparameterize after NBASE=1 base layers
      prep_mv_kernel<<<dim3(128), B, 0, stream>>>(W_mu, W_var, b_mu, b_var, Bt, bias);
      gemm_bf16_kernel<4, 16, true><<<dim3(mblk), B, 0, stream>>>(xb, Bt, bias, UVb, N);
      reparam_kernel<<<dim3(2048), B, 0, stream>>>(UVb, epsp, x, xb, kacc, totalNH);
    }
    prep_wg_kernel<<<dim3(128), B, 0, stream>>>(Wg + (size_t)l*4*256*32, bg + l*128, Bt, bias);
    hipMemsetAsync(w + o_st, 0, 514*4, stream);
    gemm_bf16_kernel<4, 16, true><<<dim3(mblk), B, 0, stream>>>(xb, Bt, bias, UVb, N);
    pq_kernel<<<dim3(2048), B, 0, stream>>>(x, Wf + l*256, bfp + l, p, q, N);
    gstat_kernel<<<dim3(1024), B, 0, stream>>>(p, q, src, dst, gstats, E);
    gate_wexp_kernel<<<dim3(256), B, 0, stream>>>(cstart, csrc, p, q, nodew, gstats,
                                                  gfp + l, befp + l, wexp, sum_w, N, invE);
    zstat_kernel<<<dim3(2048), B, 0, stream>>>(UVb, cstart, csrc, zstats, N);
    walk2_kernel<<<dim3(2048), B, 0, stream>>>(UVb, cstart, csrc, wexp, sum_w, zstats,
                                               gg + l*128, beg + l*128, h, nstats, N, invE);
    bn_act_kernel<false,true><<<dim3(2048), B, 0, stream>>>(h, nstats, gn + l*128, ben + l*128,
                                                            x, invN, x, xb, totalNH);
  }

  // ---- pooling + output ----
  pool_kernel<<<dim3(1024), B, 0, stream>>>(x, gid, pools, cnt, totalNH);
  finalize_kernel<<<dim3((NG*HID + 255)/256), B, 0, stream>>>(pools, cnt, kacc,
                                                              (float*)d_out, NG, invN);
}

// Round 6
// 2168.273 us; speedup vs baseline: 2.7245x; 1.0795x over previous
//
#include <hip/hip_runtime.h>
#include <hip/hip_bf16.h>
#include <stdint.h>

#define HID 128
#define LAYERS 5

typedef __attribute__((ext_vector_type(8))) short short8;
typedef __attribute__((ext_vector_type(4))) float f32x4;

__device__ __forceinline__ float bf2f(unsigned int u16) {
  union { unsigned int i; float f; } c; c.i = u16 << 16; return c.f;
}
__device__ __forceinline__ unsigned short f2bf(float f) {
  union { float f; unsigned int i; } c; c.f = f;
  unsigned int r = c.i + 0x7fffu + ((c.i >> 16) & 1u);
  return (unsigned short)(r >> 16);
}
// raw transcendentals: v_exp_f32 computes 2^x; expf(x)=2^(x*log2e)
__device__ __forceinline__ float fexp(float x) {
  float r; asm("v_exp_f32 %0, %1" : "=v"(r) : "v"(x * 1.44269504f)); return r;
}
__device__ __forceinline__ float frcp(float x) {
  float r; asm("v_rcp_f32 %0, %1" : "=v"(r) : "v"(x)); return r;
}
__device__ __forceinline__ float siluf(float v) { return v * frcp(1.f + fexp(-v)); }

// ---------------- bf16 MFMA GEMM: C[M, NCT*16] = A[M, KS*32] @ Bt^T + bias ---------------
template<int KS, int NCT, bool BF16OUT>
__launch_bounds__(256)
__global__ void gemm_bf16_kernel(const unsigned short* __restrict__ A,
                                 const unsigned short* __restrict__ Bt,
                                 const float* __restrict__ bias,
                                 void* __restrict__ Cv, int M) {
  constexpr int K = KS * 32;
  constexpr int SLOTS = KS * 4;
  constexpr int SSTR = (SLOTS + 7) & ~7;
  __shared__ unsigned short wlds[NCT * 16 * SSTR * 8];
  for (int i = threadIdx.x; i < NCT * 16 * SLOTS; i += 256) {
    int col = i / SLOTS, slot = i % SLOTS;
    int phys = slot ^ (col & 7);
    *(uint4*)&wlds[(col * SSTR + phys) * 8] = *(const uint4*)(Bt + (size_t)col * K + slot * 8);
  }
  __syncthreads();
  int lane = threadIdx.x & 63, wid = threadIdx.x >> 6;
  int l15 = lane & 15, l4 = lane >> 4;
  int n0 = blockIdx.x * 64 + wid * 16;
  f32x4 acc[NCT];
  #pragma unroll
  for (int ct = 0; ct < NCT; ++ct) { f32x4 z = {0.f, 0.f, 0.f, 0.f}; acc[ct] = z; }
  int ar = n0 + l15; if (ar >= M) ar = M - 1;
  #pragma unroll
  for (int kk = 0; kk < KS; ++kk) {
    short8 af = *(const short8*)(A + (size_t)ar * K + kk * 32 + l4 * 8);
    #pragma unroll
    for (int ct = 0; ct < NCT; ++ct) {
      int col = ct * 16 + l15;
      int phys = (kk * 4 + l4) ^ (col & 7);
      short8 bfr = *(const short8*)&wlds[(col * SSTR + phys) * 8];
      acc[ct] = __builtin_amdgcn_mfma_f32_16x16x32_bf16(af, bfr, acc[ct], 0, 0, 0);
    }
  }
  #pragma unroll
  for (int ct = 0; ct < NCT; ++ct) {
    int col = ct * 16 + l15;
    #pragma unroll
    for (int j = 0; j < 4; ++j) {
      int n = n0 + l4 * 4 + j;
      if (n < M) {
        float v = acc[ct][j] + bias[col];
        if (BF16OUT) ((unsigned short*)Cv)[(size_t)n * (NCT * 16) + col] = f2bf(v);
        else         ((float*)Cv)[(size_t)n * (NCT * 16) + col] = v;
      }
    }
  }
}

// ---------------- embed input/weight casts (pad K to 224) --------------------------------
__global__ void cast_atom_kernel(const float* __restrict__ atom, unsigned short* __restrict__ ab,
                                 int N, int AIN) {
  int n = blockIdx.x, k = threadIdx.x;
  if (n < N && k < 224)
    ab[(size_t)n * 224 + k] = f2bf(k < AIN ? atom[(size_t)n * AIN + k] : 0.f);
}
__global__ void prep_we_kernel(const float* __restrict__ W, unsigned short* __restrict__ Bt,
                               int AIN) {
  int i = blockIdx.x * 256 + threadIdx.x;
  if (i >= 128 * 224) return;
  int col = i / 224, k = i % 224;
  Bt[i] = f2bf(k < AIN ? W[(size_t)k * 128 + col] : 0.f);
}

// ---------------- per-feature sum/sumsq over rows (f32 input) ----------------------------
__global__ void colstats_kernel(const float* __restrict__ in, int M, float* __restrict__ stats) {
  int f = threadIdx.x & 127;
  int rl = threadIdx.x >> 7;
  float s = 0, s2 = 0;
  for (int r = blockIdx.x * 2 + rl; r < M; r += gridDim.x * 2) {
    float v = in[(size_t)r * 128 + f];
    s += v; s2 += v * v;
  }
  __shared__ float l1[256], l2[256];
  l1[threadIdx.x] = s; l2[threadIdx.x] = s2;
  __syncthreads();
  if (rl == 0) {
    atomicAdd(&stats[f],       s  + l1[128 + f]);
    atomicAdd(&stats[128 + f], s2 + l2[128 + f]);
  }
}

// ---------------- BN (+silu / +residual), writes f32 x and bf16 xb -----------------------
template<bool SILU, bool RES>
__global__ void bn_act_kernel(const float* __restrict__ in, const float* __restrict__ stats,
                              const float* __restrict__ g, const float* __restrict__ be,
                              const float* __restrict__ resid, float invM,
                              float* __restrict__ xout, unsigned short* __restrict__ xbout,
                              size_t total) {
  int f = threadIdx.x & 127;
  float mean = stats[f] * invM;
  float var  = stats[128 + f] * invM - mean * mean;
  float sc = g[f] * rsqrtf(var + 1e-5f);
  float sh = be[f] - mean * sc;
  for (size_t i = (size_t)blockIdx.x * blockDim.x + threadIdx.x; i < total;
       i += (size_t)gridDim.x * blockDim.x) {
    float v = in[i] * sc + sh;
    if (SILU) v = siluf(v);
    if (RES)  v += resid[i];
    xout[i] = v;
    xbout[i] = f2bf(v);
  }
}

// ---------------- CSR build: histogram, scan, scatter ------------------------------------
__global__ void hist_kernel(const int* __restrict__ ids, int* __restrict__ deg, int E) {
  for (int e = blockIdx.x * blockDim.x + threadIdx.x; e < E; e += gridDim.x * blockDim.x)
    atomicAdd(&deg[ids[e]], 1);
}

__global__ void scan_block_kernel(const int* __restrict__ in, int n,
                                  int* __restrict__ excl, int* __restrict__ totals) {
  __shared__ int tmp[256];
  int idx = blockIdx.x * 256 + threadIdx.x;
  int v = (idx < n) ? in[idx] : 0;
  tmp[threadIdx.x] = v;
  __syncthreads();
  for (int o = 1; o < 256; o <<= 1) {
    int t = (threadIdx.x >= o) ? tmp[threadIdx.x - o] : 0;
    __syncthreads();
    tmp[threadIdx.x] += t;
    __syncthreads();
  }
  if (idx < n) excl[idx] = tmp[threadIdx.x] - v;
  if (threadIdx.x == 255 && totals) totals[blockIdx.x] = tmp[255];
}

__global__ void scan_add_kernel(const int* __restrict__ excl, const int* __restrict__ tot_excl,
                                const int* __restrict__ indeg, int* __restrict__ cstart, int n) {
  int idx = blockIdx.x * 256 + threadIdx.x;
  if (idx < n) {
    int v = excl[idx] + tot_excl[blockIdx.x];
    cstart[idx] = v;
    if (idx == n - 1) cstart[n] = v + indeg[idx];
  }
}

__global__ void scatter_kernel(const int* __restrict__ src, const int* __restrict__ dst,
                               const int* __restrict__ cstart, int* __restrict__ fill,
                               int* __restrict__ csrc, int* __restrict__ cdst, int E) {
  for (int e = blockIdx.x * blockDim.x + threadIdx.x; e < E; e += gridDim.x * blockDim.x) {
    int d = dst[e];
    int pos = cstart[d] + atomicAdd(&fill[d], 1);
    csrc[pos] = src[e];
    cdst[pos] = d;
  }
}

// ---------------- weight preps (bf16, [col][k] layout) -----------------------------------
__global__ void prep_wg_kernel(const float* __restrict__ WgL, const float* __restrict__ bgL,
                               unsigned short* __restrict__ Bt, float* __restrict__ bias) {
  int i = blockIdx.x * 256 + threadIdx.x;
  if (i < 256 * 128) {
    int col = i >> 7, k = i & 127;
    int c = col & 127, h = c >> 5, d = c & 31;
    int krow = (col < 128) ? k : 128 + k;
    Bt[i] = f2bf(WgL[((size_t)h * 256 + krow) * 32 + d]);
  }
  if (i < 256) bias[i] = (i < 128) ? 0.f : bgL[i - 128];
}

__global__ void prep_mv_kernel(const float* __restrict__ Wm, const float* __restrict__ Wv,
                               const float* __restrict__ bm, const float* __restrict__ bv,
                               unsigned short* __restrict__ Bt, float* __restrict__ bias) {
  int i = blockIdx.x * 256 + threadIdx.x;
  if (i < 256 * 128) {
    int col = i >> 7, k = i & 127;
    Bt[i] = f2bf(col < 128 ? Wm[(size_t)k * 128 + col] : Wv[(size_t)k * 128 + col - 128]);
  }
  if (i < 256) bias[i] = (i < 128) ? bm[i] : bv[i - 128];
}

// ---------------- per-node gate scalars: p = x . Wf_src ; q = x . Wf_dst + bf ------------
__global__ void pq_kernel(const float* __restrict__ x, const float* __restrict__ WfL,
                          const float* __restrict__ bfL, float* __restrict__ p,
                          float* __restrict__ q, int N) {
  __shared__ float wf[256];
  wf[threadIdx.x] = WfL[threadIdx.x];
  __syncthreads();
  int wid = threadIdx.x >> 6, lane = threadIdx.x & 63;
  float bf0 = bfL[0];
  for (int n = blockIdx.x * 4 + wid; n < N; n += gridDim.x * 4) {
    float2 xv = *(const float2*)(x + (size_t)n * 128 + lane * 2);
    float pp = xv.x * wf[lane * 2]       + xv.y * wf[lane * 2 + 1];
    float qq = xv.x * wf[128 + lane * 2] + xv.y * wf[129 + lane * 2];
    #pragma unroll
    for (int o = 32; o; o >>= 1) { pp += __shfl_down(pp, o); qq += __shfl_down(qq, o); }
    if (lane == 0) { p[n] = pp; q[n] = qq + bf0; }
  }
}

// ---------------- gate BN stats over edges: sum/sumsq of t = p[src]+q[dst] ---------------
__global__ void gstat_kernel(const float* __restrict__ p, const float* __restrict__ q,
                             const int* __restrict__ src, const int* __restrict__ dst,
                             float* __restrict__ gstats, int E) {
  float s = 0, s2 = 0;
  for (int e = blockIdx.x * blockDim.x + threadIdx.x; e < E; e += gridDim.x * blockDim.x) {
    float t = p[src[e]] + q[dst[e]];
    s += t; s2 += t * t;
  }
  #pragma unroll
  for (int o = 32; o; o >>= 1) { s += __shfl_down(s, o); s2 += __shfl_down(s2, o); }
  __shared__ float la[4], lb[4];
  int lane = threadIdx.x & 63, wid = threadIdx.x >> 6;
  if (lane == 0) { la[wid] = s; lb[wid] = s2; }
  __syncthreads();
  if (threadIdx.x == 0) {
    atomicAdd(&gstats[0], la[0] + la[1] + la[2] + la[3]);
    atomicAdd(&gstats[1], lb[0] + lb[1] + lb[2] + lb[3]);
  }
}

// ---------------- gate apply per node (thread/node): wexp[j], sum_w[n] -------------------
__global__ void gate_wexp_kernel(const int* __restrict__ cs, const int* __restrict__ csrc,
                                 const float* __restrict__ p, const float* __restrict__ q,
                                 const float* __restrict__ nodew, const float* __restrict__ gstats,
                                 const float* __restrict__ gfL, const float* __restrict__ befL,
                                 float* __restrict__ wexp, float* __restrict__ sum_w,
                                 int N, float invE) {
  float gm  = gstats[0] * invE;
  float gv  = gstats[1] * invE - gm * gm;
  float gsc = gfL[0] * rsqrtf(gv + 1e-5f);
  float gsh = befL[0] - gm * gsc;
  for (int n = blockIdx.x * blockDim.x + threadIdx.x; n < N; n += gridDim.x * blockDim.x) {
    float qn = q[n] * gsc + gsh;
    int s0 = cs[n], s1 = cs[n + 1];
    float sw = 0;
    for (int j = s0; j < s1; ++j) {
      int sn = csrc[j];
      float v = p[sn] * gsc + qn;
      v = v * frcp(1.f + fexp(-v));
      float we = nodew[sn] * fexp(v);
      wexp[j] = we;
      sw += we;
    }
    sum_w[n] = sw;
  }
}

// ---------------- z-stats node-factorable part: sum/sumsq weighted by out/in degree ------
__global__ void zstat_node_kernel(const unsigned short* __restrict__ UVb,
                                  const int* __restrict__ indeg, const int* __restrict__ outdeg,
                                  float* __restrict__ zstats, int N) {
  int lane = threadIdx.x & 63, g = threadIdx.x >> 6;
  int f0 = lane * 2, f1 = f0 + 1;
  float zs0 = 0, zq0 = 0, zs1 = 0, zq1 = 0;
  for (int n = blockIdx.x * 4 + g; n < N; n += gridDim.x * 4) {
    float od = (float)outdeg[n], id = (float)indeg[n];
    unsigned up = *(const unsigned*)(UVb + ((size_t)n << 8) + f0);
    unsigned vp = *(const unsigned*)(UVb + ((size_t)n << 8) + 128 + f0);
    float u0 = bf2f(up & 0xffffu), u1 = bf2f(up >> 16);
    float v0 = bf2f(vp & 0xffffu), v1 = bf2f(vp >> 16);
    zs0 += od * u0 + id * v0;  zq0 += od * u0 * u0 + id * v0 * v0;
    zs1 += od * u1 + id * v1;  zq1 += od * u1 * u1 + id * v1 * v1;
  }
  __shared__ float r1[4][128], r2[4][128];
  r1[g][f0] = zs0; r1[g][f1] = zs1;
  r2[g][f0] = zq0; r2[g][f1] = zq1;
  __syncthreads();
  if (threadIdx.x < 128) {
    int f = threadIdx.x;
    atomicAdd(&zstats[f],       r1[0][f] + r1[1][f] + r1[2][f] + r1[3][f]);
    atomicAdd(&zstats[128 + f], r2[0][f] + r2[1][f] + r2[2][f] + r2[3][f]);
  }
}

// ---------------- cross term: zc[f] += sum_e U[src,f]*V[dst,f] (32-slot partials) --------
__global__ void zcross_kernel(const unsigned short* __restrict__ UVb,
                              const int* __restrict__ csrc, const int* __restrict__ cdst,
                              float* __restrict__ zc_parts, int E) {
  int lane = threadIdx.x & 63;
  int gw = (blockIdx.x * 256 + threadIdx.x) >> 6;
  int nw = (gridDim.x * 256) >> 6;
  int f0 = lane * 2;
  float cr0 = 0, cr1 = 0;
  int nch = (E + 63) >> 6;
  for (int c = gw; c < nch; c += nw) {
    int e0 = c << 6, len = min(64, E - e0);
    int ee = e0 + (lane < len ? lane : len - 1);
    int idxs = csrc[ee], idxd = cdst[ee];
    int dcur = __shfl(idxd, 0);
    float su0 = 0, su1 = 0;
    unsigned up_next = *(const unsigned*)(UVb + ((size_t)__shfl(idxs, 0) << 8) + f0);
    for (int i = 0; i < len; ++i) {
      unsigned up = up_next;
      if (i + 1 < len)
        up_next = *(const unsigned*)(UVb + ((size_t)__shfl(idxs, i + 1) << 8) + f0);
      int d = __shfl(idxd, i);
      if (d != dcur) {
        unsigned vp = *(const unsigned*)(UVb + ((size_t)dcur << 8) + 128 + f0);
        cr0 += bf2f(vp & 0xffffu) * su0; cr1 += bf2f(vp >> 16) * su1;
        su0 = su1 = 0; dcur = d;
      }
      su0 += bf2f(up & 0xffffu); su1 += bf2f(up >> 16);
    }
    unsigned vp = *(const unsigned*)(UVb + ((size_t)dcur << 8) + 128 + f0);
    cr0 += bf2f(vp & 0xffffu) * su0; cr1 += bf2f(vp >> 16) * su1;
  }
  atomicAdd(&zc_parts[(blockIdx.x & 31) * 128 + f0],     cr0);
  atomicAdd(&zc_parts[(blockIdx.x & 31) * 128 + f0 + 1], cr1);
}

// ---------------- aggregate: edge-parallel, register segments, atomic flush --------------
__global__ void walk2_kernel(const unsigned short* __restrict__ UVb,
                             const int* __restrict__ csrc, const int* __restrict__ cdst,
                             const float* __restrict__ wexp, const float* __restrict__ sum_w,
                             const float* __restrict__ zstats, const float* __restrict__ zc_parts,
                             const float* __restrict__ gg, const float* __restrict__ beg,
                             float* __restrict__ h, int E, float invE) {
  int lane = threadIdx.x & 63;
  int gw = (blockIdx.x * 256 + threadIdx.x) >> 6;
  int nw = (gridDim.x * 256) >> 6;
  int f0 = lane * 2, f1 = f0 + 1;
  float cr0 = 0, cr1 = 0;
  #pragma unroll
  for (int i2 = 0; i2 < 32; ++i2) { cr0 += zc_parts[i2 * 128 + f0]; cr1 += zc_parts[i2 * 128 + f1]; }
  float zm0 = zstats[f0] * invE;
  float zv0 = (zstats[128 + f0] + 2.f * cr0) * invE - zm0 * zm0;
  float sc0 = gg[f0] * rsqrtf(zv0 + 1e-5f), sh0 = beg[f0] - zm0 * sc0;
  float zm1 = zstats[f1] * invE;
  float zv1 = (zstats[128 + f1] + 2.f * cr1) * invE - zm1 * zm1;
  float sc1 = gg[f1] * rsqrtf(zv1 + 1e-5f), sh1 = beg[f1] - zm1 * sc1;

  int nch = (E + 63) >> 6;
  for (int c = gw; c < nch; c += nw) {
    int e0 = c << 6, len = min(64, E - e0);
    int ee = e0 + (lane < len ? lane : len - 1);
    int idxs = csrc[ee], idxd = cdst[ee];
    float wv = wexp[ee];
    int dcur = __shfl(idxd, 0);
    float inv = frcp(sum_w[dcur]);
    float c0, c1;
    { unsigned vp = *(const unsigned*)(UVb + ((size_t)dcur << 8) + 128 + f0);
      c0 = bf2f(vp & 0xffffu) * sc0 + sh0; c1 = bf2f(vp >> 16) * sc1 + sh1; }
    float h0 = 0, h1 = 0;
    unsigned up_next = *(const unsigned*)(UVb + ((size_t)__shfl(idxs, 0) << 8) + f0);
    for (int i = 0; i < len; ++i) {
      unsigned up = up_next;
      if (i + 1 < len)
        up_next = *(const unsigned*)(UVb + ((size_t)__shfl(idxs, i + 1) << 8) + f0);
      int d = __shfl(idxd, i);
      float a = __shfl(wv, i);
      if (d != dcur) {
        atomicAdd(&h[((size_t)dcur << 7) + f0], h0 * inv);
        atomicAdd(&h[((size_t)dcur << 7) + f1], h1 * inv);
        h0 = h1 = 0; dcur = d; inv = frcp(sum_w[d]);
        unsigned vp = *(const unsigned*)(UVb + ((size_t)d << 8) + 128 + f0);
        c0 = bf2f(vp & 0xffffu) * sc0 + sh0; c1 = bf2f(vp >> 16) * sc1 + sh1;
      }
      float v0 = bf2f(up & 0xffffu) * sc0 + c0;
      float v1 = bf2f(up >> 16)     * sc1 + c1;
      v0 = v0 * frcp(1.f + fexp(-v0));
      v1 = v1 * frcp(1.f + fexp(-v1));
      h0 += a * v0; h1 += a * v1;
    }
    atomicAdd(&h[((size_t)dcur << 7) + f0], h0 * inv);
    atomicAdd(&h[((size_t)dcur << 7) + f1], h1 * inv);
  }
}

// ---------------- reparameterize (bf16 muv=[mu|lv] packed [N,256]) + kld -----------------
__global__ void reparam_kernel(const unsigned short* __restrict__ muv,
                               const float* __restrict__ eps,
                               float* __restrict__ x, unsigned short* __restrict__ xb,
                               float* __restrict__ kacc, size_t total) {
  float part = 0;
  for (size_t i = (size_t)blockIdx.x * blockDim.x + threadIdx.x; i < total;
       i += (size_t)gridDim.x * blockDim.x) {
    size_t n = i >> 7; int f = (int)(i & 127);
    float m = bf2f(muv[(n << 8) + f]);
    float l = bf2f(muv[(n << 8) + 128 + f]);
    float el = fexp(l);
    float v = eps[i] * fexp(0.5f * l) + m;
    x[i] = v;
    xb[i] = f2bf(v);
    part += 1.f + l - m * m - el;
  }
  #pragma unroll
  for (int o = 32; o; o >>= 1) part += __shfl_down(part, o);
  __shared__ float la[4];
  int lane = threadIdx.x & 63, wid = threadIdx.x >> 6;
  if (lane == 0) la[wid] = part;
  __syncthreads();
  if (threadIdx.x == 0) atomicAdd(kacc, la[0] + la[1] + la[2] + la[3]);
}

// ---------------- pooling ----------------------------------------------------------------
__global__ void pool_kernel(const float* __restrict__ x, const int* __restrict__ gid,
                            float* __restrict__ pools, float* __restrict__ cnt, size_t total) {
  for (size_t i = (size_t)blockIdx.x * blockDim.x + threadIdx.x; i < total;
       i += (size_t)gridDim.x * blockDim.x) {
    int n = (int)(i >> 7), f = (int)(i & 127);
    int g = gid[n];
    atomicAdd(&pools[(size_t)g * 128 + f], x[i]);
    if (f == 0) atomicAdd(&cnt[g], 1.f);
  }
}

__global__ void finalize_kernel(const float* __restrict__ pools, const float* __restrict__ cnt,
                                const float* __restrict__ kacc, float* __restrict__ out,
                                int NG, float invN) {
  int i = blockIdx.x * blockDim.x + threadIdx.x;
  if (i < NG * 128) {
    float c = cnt[i >> 7];
    c = c > 1.f ? c : 1.f;
    out[i] = pools[i] / c;
  }
  if (i == 0) out[NG * 128] = -0.5f * kacc[0] * invN;
}

// =========================================================================================
extern "C" void kernel_launch(void* const* d_in, const int* in_sizes, int n_in,
                              void* d_out, int out_size, void* d_ws, size_t ws_size,
                              hipStream_t stream) {
  const float* atom    = (const float*)d_in[0];
  const float* nodew   = (const float*)d_in[1];
  const float* epsp    = (const float*)d_in[2];
  const int*   src     = (const int*)d_in[3];
  const int*   dst     = (const int*)d_in[4];
  const int*   gid     = (const int*)d_in[5];
  const float* W_embed = (const float*)d_in[6];
  const float* b_embed = (const float*)d_in[7];
  const float* g_embed = (const float*)d_in[8];
  const float* be_embed= (const float*)d_in[9];
  const float* Wf      = (const float*)d_in[10];
  const float* bfp     = (const float*)d_in[11];
  const float* gfp     = (const float*)d_in[12];
  const float* befp    = (const float*)d_in[13];
  const float* Wg      = (const float*)d_in[14];
  const float* bg      = (const float*)d_in[15];
  const float* gg      = (const float*)d_in[16];
  const float* beg     = (const float*)d_in[17];
  const float* gn      = (const float*)d_in[18];
  const float* ben     = (const float*)d_in[19];
  const float* W_mu    = (const float*)d_in[20];
  const float* b_mu    = (const float*)d_in[21];
  const float* W_var   = (const float*)d_in[22];
  const float* b_var   = (const float*)d_in[23];

  const int N   = in_sizes[1];
  const int E   = in_sizes[3];
  const int AIN = in_sizes[0] / N;
  const int NG  = (out_size - 1) / HID;

  char* w = (char*)d_ws;
  size_t off = 0;
  auto alloc = [&](size_t bytes) { size_t r = off; off = (off + bytes + 255) & ~(size_t)255; return r; };
  size_t o_x    = alloc((size_t)N*HID*4);
  size_t o_xb   = alloc((size_t)N*HID*2);
  size_t o_uvb  = alloc((size_t)N*256*2);    // bf16 [U|V] (also bf16 [mu|lv])
  size_t o_h    = alloc((size_t)N*HID*4);
  size_t o_ab   = alloc((size_t)N*224*2);
  size_t o_p    = alloc((size_t)N*4);
  size_t o_q    = alloc((size_t)N*4);
  size_t o_sw   = alloc((size_t)N*4);
  size_t o_wexp = alloc((size_t)E*4);
  size_t o_csrc = alloc((size_t)E*4);
  size_t o_cdst = alloc((size_t)E*4);
  size_t o_cs   = alloc((size_t)(N+1)*4);
  size_t o_deg  = alloc((size_t)3*N*4);      // indeg | fill | outdeg (single memset)
  size_t o_excl = alloc((size_t)N*4);
  size_t o_tot  = alloc(512*4);
  size_t o_bt   = alloc((size_t)256*128*2);
  size_t o_bias = alloc(256*4);
  size_t o_st   = alloc((514 + 32*128)*4);   // gate[0:2) z[2:258) node[258:514) zc_parts[514:...)
  size_t o_kp   = alloc((size_t)(64 + NG*HID + NG)*4);

  float* x              = (float*)(w + o_x);
  unsigned short* xb    = (unsigned short*)(w + o_xb);
  unsigned short* UVb   = (unsigned short*)(w + o_uvb);
  float* h              = (float*)(w + o_h);
  unsigned short* atomb = (unsigned short*)(w + o_ab);
  float* p              = (float*)(w + o_p);
  float* q              = (float*)(w + o_q);
  float* sum_w          = (float*)(w + o_sw);
  float* wexp           = (float*)(w + o_wexp);
  int*   csrc           = (int*)(w + o_csrc);
  int*   cdst           = (int*)(w + o_cdst);
  int*   cstart         = (int*)(w + o_cs);
  int*   indeg          = (int*)(w + o_deg);
  int*   fill           = indeg + N;
  int*   outdeg         = indeg + 2*N;
  int*   excl           = (int*)(w + o_excl);
  int*   totals         = (int*)(w + o_tot);
  int*   tot_excl       = totals + 256;
  unsigned short* Bt    = (unsigned short*)(w + o_bt);
  float* bias           = (float*)(w + o_bias);
  float* stats          = (float*)(w + o_st);
  float* gstats         = stats;
  float* zstats         = stats + 2;
  float* nstats         = stats + 258;
  float* zc_parts       = stats + 514;
  float* kacc           = (float*)(w + o_kp);
  float* pools          = kacc + 64;
  float* cnt            = pools + (size_t)NG*HID;

  const dim3 B(256);
  const int mblk = (N + 63) / 64;
  const int nb1  = (N + 255) / 256;
  const float invN = 1.f / (float)N;
  const float invE = 1.f / (float)E;
  const size_t totalNH = (size_t)N * HID;
  const size_t st_bytes = (514 + 32*128) * 4;

  // ---- zero accumulators ----
  hipMemsetAsync(w + o_st, 0, st_bytes, stream);
  hipMemsetAsync(w + o_kp, 0, (64 + (size_t)NG*HID + NG)*4, stream);
  hipMemsetAsync(w + o_deg, 0, (size_t)3*N*4, stream);

  // ---- CSR build (dst-sorted) + degrees ----
  hist_kernel<<<dim3(1024), B, 0, stream>>>(dst, indeg, E);
  hist_kernel<<<dim3(1024), B, 0, stream>>>(src, outdeg, E);
  scan_block_kernel<<<dim3(nb1), B, 0, stream>>>(indeg, N, excl, totals);
  scan_block_kernel<<<dim3(1), B, 0, stream>>>(totals, nb1, tot_excl, nullptr);
  scan_add_kernel<<<dim3(nb1), B, 0, stream>>>(excl, tot_excl, indeg, cstart, N);
  scatter_kernel<<<dim3(1024), B, 0, stream>>>(src, dst, cstart, fill, csrc, cdst, E);

  // ---- atom embedding ----
  cast_atom_kernel<<<dim3(N), B, 0, stream>>>(atom, atomb, N, AIN);
  prep_we_kernel<<<dim3(112), B, 0, stream>>>(W_embed, Bt, AIN);
  gemm_bf16_kernel<7, 8, false><<<dim3(mblk), B, 0, stream>>>(atomb, Bt, b_embed, h, N);
  colstats_kernel<<<dim3(512), B, 0, stream>>>(h, N, nstats);
  bn_act_kernel<true,false><<<dim3(2048), B, 0, stream>>>(h, nstats, g_embed, be_embed,
                                                          x, invN, x, xb, totalNH);

  for (int l = 0; l < LAYERS; ++l) {
    if (l == 1) {
      prep_mv_kernel<<<dim3(128), B, 0, stream>>>(W_mu, W_var, b_mu, b_var, Bt, bias);
      gemm_bf16_kernel<4, 16, true><<<dim3(mblk), B, 0, stream>>>(xb, Bt, bias, UVb, N);
      reparam_kernel<<<dim3(2048), B, 0, stream>>>(UVb, epsp, x, xb, kacc, totalNH);
    }
    prep_wg_kernel<<<dim3(128), B, 0, stream>>>(Wg + (size_t)l*4*256*32, bg + l*128, Bt, bias);
    hipMemsetAsync(w + o_st, 0, st_bytes, stream);
    hipMemsetAsync(w + o_h, 0, (size_t)N*HID*4, stream);
    gemm_bf16_kernel<4, 16, true><<<dim3(mblk), B, 0, stream>>>(xb, Bt, bias, UVb, N);
    pq_kernel<<<dim3(2048), B, 0, stream>>>(x, Wf + l*256, bfp + l, p, q, N);
    gstat_kernel<<<dim3(1024), B, 0, stream>>>(p, q, src, dst, gstats, E);
    gate_wexp_kernel<<<dim3(256), B, 0, stream>>>(cstart, csrc, p, q, nodew, gstats,
                                                  gfp + l, befp + l, wexp, sum_w, N, invE);
    zstat_node_kernel<<<dim3(512), B, 0, stream>>>(UVb, indeg, outdeg, zstats, N);
    zcross_kernel<<<dim3(2048), B, 0, stream>>>(UVb, csrc, cdst, zc_parts, E);
    walk2_kernel<<<dim3(2048), B, 0, stream>>>(UVb, csrc, cdst, wexp, sum_w, zstats, zc_parts,
                                               gg + l*128, beg + l*128, h, E, invE);
    colstats_kernel<<<dim3(512), B, 0, stream>>>(h, N, nstats);
    bn_act_kernel<false,true><<<dim3(2048), B, 0, stream>>>(h, nstats, gn + l*128, ben + l*128,
                                                            x, invN, x, xb, totalNH);
  }

  // ---- pooling + output ----
  pool_kernel<<<dim3(1024), B, 0, stream>>>(x, gid, pools, cnt, totalNH);
  finalize_kernel<<<dim3((NG*HID + 255)/256), B, 0, stream>>>(pools, cnt, kacc,
                                                              (float*)d_out, NG, invN);
}